// Round 11
// baseline (587.932 us; speedup 1.0000x reference)
//
#include <hip/hip_runtime.h>
#include <hip/hip_bf16.h>

#define ND 128
#define LDO 512
#define ALPHA 0.2f
#define L2EPS 1e-12f
#define SCAN_B 256
#define NCHUNK 256     // edge chunks for bucket hist/scatter (== SCAN_B, relied upon!)
#define RPB 512        // rows per bucket (shift 9)
#define DBIN 1024      // degree bins for row permutation

typedef __attribute__((ext_vector_type(8))) short short8;
typedef __attribute__((ext_vector_type(4))) float f32x4;
typedef __attribute__((ext_vector_type(2))) float f32x2;

__device__ __forceinline__ short f2bf(float f) {
    union { float f; unsigned u; } c; c.f = f;
    unsigned u = c.u;
    unsigned r = (u + 0x7fffu + ((u >> 16) & 1u)) >> 16;   // RNE
    return (short)r;
}
__device__ __forceinline__ float bf2f(unsigned short u) {
    union { unsigned u; float f; } c; c.u = ((unsigned)u) << 16;
    return c.f;
}
__device__ __forceinline__ void gload_lds16(const void* g, void* l) {
    __builtin_amdgcn_global_load_lds(
        (const __attribute__((address_space(1))) unsigned int*)g,
        (__attribute__((address_space(3))) unsigned int*)l, 16, 0, 0);
}

// ---------------- copy embeddings into out[:, 0:128], xb (bf16), xf8 (fp8) ----------------
__global__ void copy_emb_kernel(const float* __restrict__ emb, float* __restrict__ out,
                                unsigned short* __restrict__ xb,
                                unsigned int* __restrict__ xf8w, int n) {
    int idx = blockIdx.x * blockDim.x + threadIdx.x;
    int total = n * 32;
    if (idx >= total) return;
    int r = idx >> 5, c4 = idx & 31;
    const float4 v = *reinterpret_cast<const float4*>(emb + (size_t)r * ND + c4 * 4);
    *reinterpret_cast<float4*>(out + (size_t)r * LDO + c4 * 4) = v;
    ushort4 b;
    b.x = (unsigned short)f2bf(v.x); b.y = (unsigned short)f2bf(v.y);
    b.z = (unsigned short)f2bf(v.z); b.w = (unsigned short)f2bf(v.w);
    *reinterpret_cast<ushort4*>(xb + (size_t)r * ND + c4 * 4) = b;
    unsigned int u = __builtin_amdgcn_cvt_pk_fp8_f32(v.x, v.y, 0, false);
    u = __builtin_amdgcn_cvt_pk_fp8_f32(v.z, v.w, u, true);
    xf8w[(size_t)r * 32 + c4] = u;
}

// ---------------- pass A: per-chunk bucket histogram (LDS only) ----------------
__global__ __launch_bounds__(256) void bucket_hist_kernel(const int* __restrict__ erow,
                                                          int* __restrict__ gcnt,
                                                          int n_edges, int nb, int ch) {
    __shared__ int cnt[256];
    int b = blockIdx.x;
    cnt[threadIdx.x] = 0;
    __syncthreads();
    int s = b * ch, e = min(n_edges, s + ch);
    for (int j = s + threadIdx.x; j < e; j += 256) {
        atomicAdd(&cnt[erow[j] >> 9], 1);
    }
    __syncthreads();
    for (int i = threadIdx.x; i < nb; i += 256) gcnt[i * NCHUNK + b] = cnt[i];
}

// ---------------- scans ----------------
__global__ __launch_bounds__(SCAN_B) void scanA_kernel(const int* __restrict__ in,
                                                       int* __restrict__ outp,
                                                       int* __restrict__ partials, int n) {
    __shared__ int sm[SCAN_B];
    int i = blockIdx.x * SCAN_B + threadIdx.x;
    int v = (i < n) ? in[i] : 0;
    sm[threadIdx.x] = v;
    __syncthreads();
#pragma unroll
    for (int off = 1; off < SCAN_B; off <<= 1) {
        int t = (threadIdx.x >= off) ? sm[threadIdx.x - off] : 0;
        __syncthreads();
        sm[threadIdx.x] += t;
        __syncthreads();
    }
    if (i < n) outp[i] = sm[threadIdx.x] - v;
    if (threadIdx.x == SCAN_B - 1) partials[blockIdx.x] = sm[SCAN_B - 1];
}

__global__ __launch_bounds__(512) void scanB_kernel(int* __restrict__ partials, int nb) {
    __shared__ int sm[512];
    int v = (threadIdx.x < nb) ? partials[threadIdx.x] : 0;
    sm[threadIdx.x] = v;
    __syncthreads();
#pragma unroll
    for (int off = 1; off < 512; off <<= 1) {
        int t = (threadIdx.x >= off) ? sm[threadIdx.x - off] : 0;
        __syncthreads();
        sm[threadIdx.x] += t;
        __syncthreads();
    }
    if (threadIdx.x < nb) partials[threadIdx.x] = sm[threadIdx.x] - v;
}

// ---------------- pass B: scatter into bucket-grouped tmp ----------------
__global__ __launch_bounds__(256) void bucket_scatter_kernel(const int* __restrict__ erow,
                                                             const int* __restrict__ ecol,
                                                             const float* __restrict__ eval,
                                                             const int* __restrict__ gscan,
                                                             const int* __restrict__ part,
                                                             int2* __restrict__ tmp,
                                                             int n_edges, int nb, int ch) {
    __shared__ int cur[256];
    int b = blockIdx.x;
    for (int i = threadIdx.x; i < nb; i += 256)
        cur[i] = gscan[i * NCHUNK + b] + part[i];
    __syncthreads();
    int s = b * ch, e = min(n_edges, s + ch);
    for (int j = s + threadIdx.x; j < e; j += 256) {
        int r = erow[j];
        int pos = atomicAdd(&cur[r >> 9], 1);
        int2 p;
        p.x = ecol[j] | ((r & (RPB - 1)) << 17);     // col (17b) | row-low (9b)
        p.y = __float_as_int(eval[j]);
        tmp[pos] = p;
    }
}

// ---------------- pass C: per-bucket counting sort into CSR pv + row_start + deg hist ----
__global__ __launch_bounds__(256) void bucket_sort_kernel(const int2* __restrict__ tmp,
                                                          const int* __restrict__ gscan,
                                                          const int* __restrict__ part,
                                                          int2* __restrict__ pv,
                                                          int* __restrict__ row_start,
                                                          int* __restrict__ deg_hist,
                                                          int n, int n_edges, int nb) {
    __shared__ int hist[RPB];
    __shared__ int cur[RPB];
    __shared__ int sc[256];
    const int t = threadIdx.x;
    const int bkt = blockIdx.x;
    const int r0 = bkt << 9;
    const int s = gscan[bkt * NCHUNK] + part[bkt];
    const int e = (bkt + 1 < nb) ? (gscan[(bkt + 1) * NCHUNK] + part[bkt + 1]) : n_edges;

    for (int i = t; i < RPB; i += 256) hist[i] = 0;
    __syncthreads();
    for (int j = s + t; j < e; j += 256) atomicAdd(&hist[tmp[j].x >> 17], 1);
    __syncthreads();
    int a0 = hist[2 * t], a1 = hist[2 * t + 1];
    // degree histogram (only for real rows)
    if (r0 + 2 * t < n)     atomicAdd(&deg_hist[min(a0, DBIN - 1)], 1);
    if (r0 + 2 * t + 1 < n) atomicAdd(&deg_hist[min(a1, DBIN - 1)], 1);
    sc[t] = a0 + a1;
    __syncthreads();
#pragma unroll
    for (int off = 1; off < 256; off <<= 1) {
        int v = (t >= off) ? sc[t - off] : 0;
        __syncthreads();
        sc[t] += v;
        __syncthreads();
    }
    int base = s + sc[t] - a0 - a1;
    cur[2 * t] = base;
    cur[2 * t + 1] = base + a0;
    __syncthreads();
    int r1 = min(n, r0 + RPB);
    for (int i = t; i < r1 - r0; i += 256) row_start[r0 + i] = cur[i];
    if (t == 0 && r1 == n) row_start[n] = n_edges;
    __syncthreads();
    for (int j = s + t; j < e; j += 256) {
        int2 p = tmp[j];
        int pos = atomicAdd(&cur[p.x >> 17], 1);
        int2 q;
        q.x = p.x & 0x1FFFF;
        q.y = p.y;
        pv[pos] = q;
    }
}

// ---------------- degree scan (exclusive, single block) ----------------
__global__ __launch_bounds__(DBIN) void deg_scan_kernel(int* __restrict__ deg) {
    __shared__ int sm[DBIN];
    int t = threadIdx.x;
    int v = deg[t];
    sm[t] = v;
    __syncthreads();
#pragma unroll
    for (int off = 1; off < DBIN; off <<= 1) {
        int u = (t >= off) ? sm[t - off] : 0;
        __syncthreads();
        sm[t] += u;
        __syncthreads();
    }
    deg[t] = sm[t] - v;   // exclusive base
}

// ---------------- degree scatter: rowperm = rows sorted by degree ----------------
__global__ __launch_bounds__(256) void deg_scatter_kernel(const int* __restrict__ row_start,
                                                          int* __restrict__ deg_base,
                                                          int* __restrict__ rowperm, int n) {
    __shared__ int lh[DBIN];
    __shared__ int lbase[DBIN];
    int t = threadIdx.x;
    for (int i = t; i < DBIN; i += 256) lh[i] = 0;
    __syncthreads();
    int r = blockIdx.x * 256 + t;
    int d = 0, lpos = 0;
    bool valid = (r < n);
    if (valid) {
        d = min(row_start[r + 1] - row_start[r], DBIN - 1);
        lpos = atomicAdd(&lh[d], 1);
    }
    __syncthreads();
    for (int i = t; i < DBIN; i += 256) {
        int c = lh[i];
        if (c) lbase[i] = atomicAdd(&deg_base[i], c);
    }
    __syncthreads();
    if (valid) rowperm[lbase[d] + lpos] = r;
}

// ---------------- SPMM (fp8 gather, 8 lanes/row, degree-sorted rows) -> Axm ----------
// 8 lanes per row (uint4 = 16 fp8 per lane), 32 rows per 256-thread block.
__global__ __launch_bounds__(256) void spmm_axm_kernel(const int* __restrict__ row_start,
                                                       const int* __restrict__ rowperm,
                                                       const int2* __restrict__ pv,
                                                       const unsigned char* __restrict__ xf8,
                                                       const unsigned short* __restrict__ xb,
                                                       unsigned short* __restrict__ Axm, int n) {
    int idx = blockIdx.x * 32 + (threadIdx.x >> 3);
    if (idx >= n) return;
    int r = rowperm[idx];
    int l = threadIdx.x & 7;         // lane within row; elems l*16 .. l*16+15
    int s = row_start[r], e = row_start[r + 1];
    float a[16];
#pragma unroll
    for (int q = 0; q < 16; ++q) a[q] = 0.f;
    int j = s;
    for (; j + 1 < e; j += 2) {
        int2 p0 = pv[j], p1 = pv[j + 1];
        uint4 q0 = *reinterpret_cast<const uint4*>(xf8 + (size_t)p0.x * ND + l * 16);
        uint4 q1 = *reinterpret_cast<const uint4*>(xf8 + (size_t)p1.x * ND + l * 16);
        float v0 = __int_as_float(p0.y), v1 = __int_as_float(p1.y);
        f32x2 c;
        c = __builtin_amdgcn_cvt_pk_f32_fp8(q0.x, false); a[0]  += v0 * c.x; a[1]  += v0 * c.y;
        c = __builtin_amdgcn_cvt_pk_f32_fp8(q0.x, true);  a[2]  += v0 * c.x; a[3]  += v0 * c.y;
        c = __builtin_amdgcn_cvt_pk_f32_fp8(q0.y, false); a[4]  += v0 * c.x; a[5]  += v0 * c.y;
        c = __builtin_amdgcn_cvt_pk_f32_fp8(q0.y, true);  a[6]  += v0 * c.x; a[7]  += v0 * c.y;
        c = __builtin_amdgcn_cvt_pk_f32_fp8(q0.z, false); a[8]  += v0 * c.x; a[9]  += v0 * c.y;
        c = __builtin_amdgcn_cvt_pk_f32_fp8(q0.z, true);  a[10] += v0 * c.x; a[11] += v0 * c.y;
        c = __builtin_amdgcn_cvt_pk_f32_fp8(q0.w, false); a[12] += v0 * c.x; a[13] += v0 * c.y;
        c = __builtin_amdgcn_cvt_pk_f32_fp8(q0.w, true);  a[14] += v0 * c.x; a[15] += v0 * c.y;
        c = __builtin_amdgcn_cvt_pk_f32_fp8(q1.x, false); a[0]  += v1 * c.x; a[1]  += v1 * c.y;
        c = __builtin_amdgcn_cvt_pk_f32_fp8(q1.x, true);  a[2]  += v1 * c.x; a[3]  += v1 * c.y;
        c = __builtin_amdgcn_cvt_pk_f32_fp8(q1.y, false); a[4]  += v1 * c.x; a[5]  += v1 * c.y;
        c = __builtin_amdgcn_cvt_pk_f32_fp8(q1.y, true);  a[6]  += v1 * c.x; a[7]  += v1 * c.y;
        c = __builtin_amdgcn_cvt_pk_f32_fp8(q1.z, false); a[8]  += v1 * c.x; a[9]  += v1 * c.y;
        c = __builtin_amdgcn_cvt_pk_f32_fp8(q1.z, true);  a[10] += v1 * c.x; a[11] += v1 * c.y;
        c = __builtin_amdgcn_cvt_pk_f32_fp8(q1.w, false); a[12] += v1 * c.x; a[13] += v1 * c.y;
        c = __builtin_amdgcn_cvt_pk_f32_fp8(q1.w, true);  a[14] += v1 * c.x; a[15] += v1 * c.y;
    }
    if (j < e) {
        int2 p0 = pv[j];
        uint4 q0 = *reinterpret_cast<const uint4*>(xf8 + (size_t)p0.x * ND + l * 16);
        float v0 = __int_as_float(p0.y);
        f32x2 c;
        c = __builtin_amdgcn_cvt_pk_f32_fp8(q0.x, false); a[0]  += v0 * c.x; a[1]  += v0 * c.y;
        c = __builtin_amdgcn_cvt_pk_f32_fp8(q0.x, true);  a[2]  += v0 * c.x; a[3]  += v0 * c.y;
        c = __builtin_amdgcn_cvt_pk_f32_fp8(q0.y, false); a[4]  += v0 * c.x; a[5]  += v0 * c.y;
        c = __builtin_amdgcn_cvt_pk_f32_fp8(q0.y, true);  a[6]  += v0 * c.x; a[7]  += v0 * c.y;
        c = __builtin_amdgcn_cvt_pk_f32_fp8(q0.z, false); a[8]  += v0 * c.x; a[9]  += v0 * c.y;
        c = __builtin_amdgcn_cvt_pk_f32_fp8(q0.z, true);  a[10] += v0 * c.x; a[11] += v0 * c.y;
        c = __builtin_amdgcn_cvt_pk_f32_fp8(q0.w, false); a[12] += v0 * c.x; a[13] += v0 * c.y;
        c = __builtin_amdgcn_cvt_pk_f32_fp8(q0.w, true);  a[14] += v0 * c.x; a[15] += v0 * c.y;
    }
    // own x row (streaming, bf16 precision)
    const unsigned short* xr = xb + (size_t)r * ND + l * 16;
    short8 xv0 = *reinterpret_cast<const short8*>(xr);
    short8 xv1 = *reinterpret_cast<const short8*>(xr + 8);
    short8 pr0, pr1, xm0, xm1;
#pragma unroll
    for (int q = 0; q < 8; ++q) {
        float x0 = bf2f((unsigned short)xv0[q]);
        float x1 = bf2f((unsigned short)xv1[q]);
        pr0[q] = f2bf(x0 + a[q]);
        xm0[q] = f2bf(x0 * a[q]);
        pr1[q] = f2bf(x1 + a[8 + q]);
        xm1[q] = f2bf(x1 * a[8 + q]);
    }
    int sz = r & 7;
    int c0 = 2 * l, c1 = 2 * l + 1;
    unsigned short* rowp = Axm + (size_t)r * 256;
    *reinterpret_cast<short8*>(rowp + ((c0        ^ sz) << 3)) = pr0;
    *reinterpret_cast<short8*>(rowp + ((c1        ^ sz) << 3)) = pr1;
    *reinterpret_cast<short8*>(rowp + (((16 + c0) ^ sz) << 3)) = xm0;
    *reinterpret_cast<short8*>(rowp + (((16 + c1) ^ sz) << 3)) = xm1;
}

// ---------------- prep: Wt2[layer][h][nr][..] pre-swizzled bf16, bsum = bgc+bbi ----------
__global__ void prep_w_kernel(const float* __restrict__ Wgc, const float* __restrict__ bgc,
                              const float* __restrict__ Wbi, const float* __restrict__ bbi,
                              short* __restrict__ Wt2, float* __restrict__ bsum) {
    int z = blockIdx.x;
    int k = blockIdx.y;            // K index within half, 0..127
    int t = threadIdx.x;
    int nn = t & 127;              // N index
    int h  = (t < 128) ? 0 : 1;    // half 0 = Wgc (prop), 1 = Wbi (xm)
    const float* src = h ? (Wbi + ((size_t)z * 128 + k) * 128)
                         : (Wgc + ((size_t)z * 128 + k) * 128);
    float v = src[nn];
    int idx16 = k >> 3, e8 = k & 7;
    size_t addr = ((size_t)(z * 2 + h) * 128 + nn) * 128 + ((idx16 ^ (nn & 7)) << 3) + e8;
    Wt2[addr] = f2bf(v);
    if (k == 0 && t < 128) bsum[z * 128 + t] = bgc[z * 128 + t] + bbi[z * 128 + t];
}

// ---------------- fused layer via MFMA (pure-copy staging) ----------------
__global__ __launch_bounds__(256) void fused_layer_mfma(
        const unsigned short* __restrict__ Axm,   // [(n+pad)][256] pre-swizzled
        const short* __restrict__ Wt2,            // [2][128][128] pre-swizzled (layer base)
        const float* __restrict__ bsum,           // [128]
        float* __restrict__ xout,                 // row stride LDO (fp32 out slice)
        unsigned short* __restrict__ xbout,       // [n][128] bf16 shadow (next x)
        unsigned char* __restrict__ xf8out,       // [n][128] fp8 shadow (next x)
        int n) {
    __shared__ short A_lds[64 * 256];    // 32 KB
    __shared__ short W_lds[128 * 128];   // 32 KB

    const int tid  = threadIdx.x;
    const int row0 = blockIdx.x * 64;
    const int lane = tid & 63;
    const int w    = tid >> 6;
    const int lrow = lane & 15;
    const int kgrp = lane >> 4;

    // ---- async stage: A tile (32KB) + W half 0 (32KB), both LDS-linear copies ----
    {
        const char* gA = (const char*)(Axm + (size_t)row0 * 256) + w * 8192 + lane * 16;
        char*       lA = (char*)A_lds + w * 8192;
        const char* gW = (const char*)Wt2 + w * 8192 + lane * 16;
        char*       lW = (char*)W_lds + w * 8192;
#pragma unroll
        for (int it = 0; it < 8; ++it) {
            gload_lds16(gA + it * 1024, lA + it * 1024);
            gload_lds16(gW + it * 1024, lW + it * 1024);
        }
    }
    asm volatile("s_waitcnt vmcnt(0)" ::: "memory");
    __syncthreads();

    f32x4 acc[8];
#pragma unroll
    for (int nf = 0; nf < 8; ++nf) acc[nf] = (f32x4){0.f, 0.f, 0.f, 0.f};

    const int ar  = w * 16 + lrow;
    const int as_ = ar & 7;

    // ---- half 0 (prop @ Wgc) ----
#pragma unroll
    for (int ksl = 0; ksl < 4; ++ksl) {
        int kkl = ksl * 4 + kgrp;                    // 0..15
        short8 af = *reinterpret_cast<const short8*>(&A_lds[ar * 256 + ((kkl ^ as_) << 3)]);
#pragma unroll
        for (int nf = 0; nf < 8; ++nf) {
            int nr = nf * 16 + lrow;
            short8 bfr = *reinterpret_cast<const short8*>(&W_lds[nr * 128 + ((kkl ^ (nr & 7)) << 3)]);
            acc[nf] = __builtin_amdgcn_mfma_f32_16x16x32_bf16(af, bfr, acc[nf], 0, 0, 0);
        }
    }
    __syncthreads();
    // ---- stage W half 1 ----
    {
        const char* gW = (const char*)Wt2 + 32768 + w * 8192 + lane * 16;
        char*       lW = (char*)W_lds + w * 8192;
#pragma unroll
        for (int it = 0; it < 8; ++it) gload_lds16(gW + it * 1024, lW + it * 1024);
    }
    asm volatile("s_waitcnt vmcnt(0)" ::: "memory");
    __syncthreads();

    // ---- half 1 (xm @ Wbi) ----
#pragma unroll
    for (int ksl = 0; ksl < 4; ++ksl) {
        int kkl = ksl * 4 + kgrp;
        short8 af = *reinterpret_cast<const short8*>(&A_lds[ar * 256 + (((16 + kkl) ^ as_) << 3)]);
#pragma unroll
        for (int nf = 0; nf < 8; ++nf) {
            int nr = nf * 16 + lrow;
            short8 bfr = *reinterpret_cast<const short8*>(&W_lds[nr * 128 + ((kkl ^ (nr & 7)) << 3)]);
            acc[nf] = __builtin_amdgcn_mfma_f32_16x16x32_bf16(af, bfr, acc[nf], 0, 0, 0);
        }
    }

    // ---- epilogue: bias + leaky + row l2-norm; out via nontemporal, bf16 + fp8 shadows ----
    float bsv[8];
#pragma unroll
    for (int nf = 0; nf < 8; ++nf) bsv[nf] = bsum[nf * 16 + lrow];

#pragma unroll
    for (int reg = 0; reg < 4; ++reg) {
        int grow = row0 + w * 16 + kgrp * 4 + reg;
        float v[8];
        float ssq = 0.f;
#pragma unroll
        for (int nf = 0; nf < 8; ++nf) {
            float tv = acc[nf][reg] + bsv[nf];
            tv = tv > 0.f ? tv : ALPHA * tv;
            v[nf] = tv;
            ssq += tv * tv;
        }
        ssq += __shfl_xor(ssq, 1);
        ssq += __shfl_xor(ssq, 2);
        ssq += __shfl_xor(ssq, 4);
        ssq += __shfl_xor(ssq, 8);
        float sc = 1.0f / sqrtf(fmaxf(ssq, L2EPS));
        if (grow < n) {
            float* op = xout + (size_t)grow * LDO;
            unsigned short* bp = xbout + (size_t)grow * ND;
            unsigned char* fp = xf8out + (size_t)grow * ND;
#pragma unroll
            for (int nf = 0; nf < 8; ++nf) {
                float ov = v[nf] * sc;
                __builtin_nontemporal_store(ov, op + nf * 16 + lrow);   // out never re-read
                bp[nf * 16 + lrow] = (unsigned short)f2bf(ov);
                unsigned int u8 = __builtin_amdgcn_cvt_pk_fp8_f32(ov, ov, 0, false);
                fp[nf * 16 + lrow] = (unsigned char)(u8 & 0xff);
            }
        }
    }
}

extern "C" void kernel_launch(void* const* d_in, const int* in_sizes, int n_in,
                              void* d_out, int out_size, void* d_ws, size_t ws_size,
                              hipStream_t stream) {
    const float* emb  = (const float*)d_in[0];
    const int*   erow = (const int*)d_in[1];
    const int*   ecol = (const int*)d_in[2];
    const float* eval = (const float*)d_in[3];
    const float* Wgc  = (const float*)d_in[4];
    const float* bgc  = (const float*)d_in[5];
    const float* Wbi  = (const float*)d_in[6];
    const float* bbi  = (const float*)d_in[7];
    float* out = (float*)d_out;

    const int n        = in_sizes[0] / ND;      // 100000
    const int n_edges  = in_sizes[1];           // 1600000
    const int n_layers = in_sizes[5] / ND;      // 3

    const int nb = (n + RPB - 1) >> 9;          // 196 buckets
    const int ch = (n_edges + NCHUNK - 1) / NCHUNK;
    const int ng = nb * NCHUNK;

    // ---- workspace layout (256B-aligned) ----
    char* ws = (char*)d_ws;
    size_t off = 0;
    auto alloc = [&](size_t bytes) { void* p = ws + off; off = (off + bytes + 255) & ~(size_t)255; return p; };
    unsigned short* xb  = (unsigned short*)alloc((size_t)n * ND * sizeof(short));        // 25.6 MB
    unsigned char*  xf8 = (unsigned char*) alloc((size_t)n * ND);                        // 12.8 MB
    unsigned short* Axm = (unsigned short*)alloc((size_t)(n + 64) * 256 * sizeof(short)); // 51.2 MB (+pad)
    int2*  pv        = (int2*) alloc((size_t)n_edges * sizeof(int2));                    // 12.8 MB
    int2*  tmp       = (int2*) alloc((size_t)n_edges * sizeof(int2));                    // 12.8 MB
    int*   row_start = (int*)  alloc((size_t)(n + 1) * sizeof(int));
    int*   rowperm   = (int*)  alloc((size_t)n * sizeof(int));
    int*   gcnt      = (int*)  alloc((size_t)ng * sizeof(int));
    int*   gscan     = (int*)  alloc((size_t)ng * sizeof(int));
    int*   partials  = (int*)  alloc(512 * sizeof(int));
    int*   deg_hist  = (int*)  alloc(DBIN * sizeof(int));
    short* Wt2       = (short*)alloc((size_t)n_layers * 2 * 128 * 128 * sizeof(short));
    float* bsum      = (float*)alloc((size_t)n_layers * 128 * sizeof(float));
    (void)ws_size;

    // ---- x0 -> out[:, 0:128] + xb + xf8 ----
    {
        int total = n * 32;
        copy_emb_kernel<<<(total + 255) / 256, 256, 0, stream>>>(emb, out, xb,
                                                                 (unsigned int*)xf8, n);
    }

    // ---- weight prep ----
    {
        dim3 g(n_layers, 128);
        prep_w_kernel<<<g, 256, 0, stream>>>(Wgc, bgc, Wbi, bbi, Wt2, bsum);
    }

    // ---- CSR build ----
    hipMemsetAsync(deg_hist, 0, DBIN * sizeof(int), stream);
    bucket_hist_kernel<<<NCHUNK, 256, 0, stream>>>(erow, gcnt, n_edges, nb, ch);
    {
        int nblk = (ng + SCAN_B - 1) / SCAN_B;     // 196
        scanA_kernel<<<nblk, SCAN_B, 0, stream>>>(gcnt, gscan, partials, ng);
        scanB_kernel<<<1, 512, 0, stream>>>(partials, nblk);
    }
    bucket_scatter_kernel<<<NCHUNK, 256, 0, stream>>>(erow, ecol, eval, gscan, partials,
                                                      tmp, n_edges, nb, ch);
    bucket_sort_kernel<<<nb, 256, 0, stream>>>(tmp, gscan, partials, pv, row_start,
                                               deg_hist, n, n_edges, nb);
    deg_scan_kernel<<<1, DBIN, 0, stream>>>(deg_hist);
    deg_scatter_kernel<<<(n + 255) / 256, 256, 0, stream>>>(row_start, deg_hist, rowperm, n);

    // ---- layers ----
    for (int i = 0; i < n_layers; ++i) {
        spmm_axm_kernel<<<(n + 31) / 32, 256, 0, stream>>>(row_start, rowperm, pv, xf8, xb,
                                                           Axm, n);
        fused_layer_mfma<<<(n + 63) / 64, 256, 0, stream>>>(
            Axm, Wt2 + (size_t)i * 2 * 128 * 128, bsum + (size_t)i * 128,
            out + (size_t)(i + 1) * ND, xb, xf8, n);
    }
}

// Round 12
// 341.158 us; speedup vs baseline: 1.7233x; 1.7233x over previous
//
#include <hip/hip_runtime.h>
#include <hip/hip_bf16.h>

#define ND 128
#define LDO 512
#define ALPHA 0.2f
#define L2EPS 1e-12f
#define SCAN_B 256
#define NCHUNK 256     // edge chunks for bucket hist/scatter (== SCAN_B, relied upon!)
#define RPB 512        // rows per bucket (shift 9)
#define DBIN 1024      // degree bins for row permutation

typedef __attribute__((ext_vector_type(8))) short short8;
typedef __attribute__((ext_vector_type(4))) float f32x4;
typedef __attribute__((ext_vector_type(2))) float f32x2;

__device__ __forceinline__ short f2bf(float f) {
    union { float f; unsigned u; } c; c.f = f;
    unsigned u = c.u;
    unsigned r = (u + 0x7fffu + ((u >> 16) & 1u)) >> 16;   // RNE
    return (short)r;
}
__device__ __forceinline__ float bf2f(unsigned short u) {
    union { unsigned u; float f; } c; c.u = ((unsigned)u) << 16;
    return c.f;
}
__device__ __forceinline__ void gload_lds16(const void* g, void* l) {
    __builtin_amdgcn_global_load_lds(
        (const __attribute__((address_space(1))) unsigned int*)g,
        (__attribute__((address_space(3))) unsigned int*)l, 16, 0, 0);
}

// ---------------- copy embeddings into out[:, 0:128], xb (bf16), xf8 (fp8) ----------------
__global__ void copy_emb_kernel(const float* __restrict__ emb, float* __restrict__ out,
                                unsigned short* __restrict__ xb,
                                unsigned int* __restrict__ xf8w, int n) {
    int idx = blockIdx.x * blockDim.x + threadIdx.x;
    int total = n * 32;
    if (idx >= total) return;
    int r = idx >> 5, c4 = idx & 31;
    const float4 v = *reinterpret_cast<const float4*>(emb + (size_t)r * ND + c4 * 4);
    *reinterpret_cast<float4*>(out + (size_t)r * LDO + c4 * 4) = v;
    ushort4 b;
    b.x = (unsigned short)f2bf(v.x); b.y = (unsigned short)f2bf(v.y);
    b.z = (unsigned short)f2bf(v.z); b.w = (unsigned short)f2bf(v.w);
    *reinterpret_cast<ushort4*>(xb + (size_t)r * ND + c4 * 4) = b;
    unsigned int u = __builtin_amdgcn_cvt_pk_fp8_f32(v.x, v.y, 0, false);
    u = __builtin_amdgcn_cvt_pk_fp8_f32(v.z, v.w, u, true);
    xf8w[(size_t)r * 32 + c4] = u;
}

// ---------------- pass A: per-chunk bucket histogram (LDS only) ----------------
__global__ __launch_bounds__(256) void bucket_hist_kernel(const int* __restrict__ erow,
                                                          int* __restrict__ gcnt,
                                                          int n_edges, int nb, int ch) {
    __shared__ int cnt[256];
    int b = blockIdx.x;
    cnt[threadIdx.x] = 0;
    __syncthreads();
    int s = b * ch, e = min(n_edges, s + ch);
    for (int j = s + threadIdx.x; j < e; j += 256) {
        atomicAdd(&cnt[erow[j] >> 9], 1);
    }
    __syncthreads();
    for (int i = threadIdx.x; i < nb; i += 256) gcnt[i * NCHUNK + b] = cnt[i];
}

// ---------------- scans ----------------
__global__ __launch_bounds__(SCAN_B) void scanA_kernel(const int* __restrict__ in,
                                                       int* __restrict__ outp,
                                                       int* __restrict__ partials, int n) {
    __shared__ int sm[SCAN_B];
    int i = blockIdx.x * SCAN_B + threadIdx.x;
    int v = (i < n) ? in[i] : 0;
    sm[threadIdx.x] = v;
    __syncthreads();
#pragma unroll
    for (int off = 1; off < SCAN_B; off <<= 1) {
        int t = (threadIdx.x >= off) ? sm[threadIdx.x - off] : 0;
        __syncthreads();
        sm[threadIdx.x] += t;
        __syncthreads();
    }
    if (i < n) outp[i] = sm[threadIdx.x] - v;
    if (threadIdx.x == SCAN_B - 1) partials[blockIdx.x] = sm[SCAN_B - 1];
}

__global__ __launch_bounds__(512) void scanB_kernel(int* __restrict__ partials, int nb) {
    __shared__ int sm[512];
    int v = (threadIdx.x < nb) ? partials[threadIdx.x] : 0;
    sm[threadIdx.x] = v;
    __syncthreads();
#pragma unroll
    for (int off = 1; off < 512; off <<= 1) {
        int t = (threadIdx.x >= off) ? sm[threadIdx.x - off] : 0;
        __syncthreads();
        sm[threadIdx.x] += t;
        __syncthreads();
    }
    if (threadIdx.x < nb) partials[threadIdx.x] = sm[threadIdx.x] - v;
}

// ---------------- pass B: scatter into bucket-grouped tmp ----------------
__global__ __launch_bounds__(256) void bucket_scatter_kernel(const int* __restrict__ erow,
                                                             const int* __restrict__ ecol,
                                                             const float* __restrict__ eval,
                                                             const int* __restrict__ gscan,
                                                             const int* __restrict__ part,
                                                             int2* __restrict__ tmp,
                                                             int n_edges, int nb, int ch) {
    __shared__ int cur[256];
    int b = blockIdx.x;
    for (int i = threadIdx.x; i < nb; i += 256)
        cur[i] = gscan[i * NCHUNK + b] + part[i];
    __syncthreads();
    int s = b * ch, e = min(n_edges, s + ch);
    for (int j = s + threadIdx.x; j < e; j += 256) {
        int r = erow[j];
        int pos = atomicAdd(&cur[r >> 9], 1);
        int2 p;
        p.x = ecol[j] | ((r & (RPB - 1)) << 17);     // col (17b) | row-low (9b)
        p.y = __float_as_int(eval[j]);
        tmp[pos] = p;
    }
}

// ---------------- pass C: counting sort into CSR pv + row_start + LDS-aggregated deg hist ----
__global__ __launch_bounds__(256) void bucket_sort_kernel(const int2* __restrict__ tmp,
                                                          const int* __restrict__ gscan,
                                                          const int* __restrict__ part,
                                                          int2* __restrict__ pv,
                                                          int* __restrict__ row_start,
                                                          int* __restrict__ deg_hist,
                                                          int n, int n_edges, int nb) {
    __shared__ int hist[RPB];
    __shared__ int cur[RPB];
    __shared__ int sc[256];
    __shared__ int dh[DBIN];
    const int t = threadIdx.x;
    const int bkt = blockIdx.x;
    const int r0 = bkt << 9;
    const int s = gscan[bkt * NCHUNK] + part[bkt];
    const int e = (bkt + 1 < nb) ? (gscan[(bkt + 1) * NCHUNK] + part[bkt + 1]) : n_edges;

    for (int i = t; i < RPB; i += 256) hist[i] = 0;
    for (int i = t; i < DBIN; i += 256) dh[i] = 0;
    __syncthreads();
    for (int j = s + t; j < e; j += 256) atomicAdd(&hist[tmp[j].x >> 17], 1);
    __syncthreads();
    int a0 = hist[2 * t], a1 = hist[2 * t + 1];
    // degree histogram -> LDS first (real rows only), flushed per-block below
    if (r0 + 2 * t < n)     atomicAdd(&dh[min(a0, DBIN - 1)], 1);
    if (r0 + 2 * t + 1 < n) atomicAdd(&dh[min(a1, DBIN - 1)], 1);
    sc[t] = a0 + a1;
    __syncthreads();
#pragma unroll
    for (int off = 1; off < 256; off <<= 1) {
        int v = (t >= off) ? sc[t - off] : 0;
        __syncthreads();
        sc[t] += v;
        __syncthreads();
    }
    int base = s + sc[t] - a0 - a1;
    cur[2 * t] = base;
    cur[2 * t + 1] = base + a0;
    __syncthreads();
    int r1 = min(n, r0 + RPB);
    for (int i = t; i < r1 - r0; i += 256) row_start[r0 + i] = cur[i];
    if (t == 0 && r1 == n) row_start[n] = n_edges;
    // flush degree histogram: one global atomic per nonzero bin per block
    for (int i = t; i < DBIN; i += 256) {
        int c = dh[i];
        if (c) atomicAdd(&deg_hist[i], c);
    }
    __syncthreads();
    for (int j = s + t; j < e; j += 256) {
        int2 p = tmp[j];
        int pos = atomicAdd(&cur[p.x >> 17], 1);
        int2 q;
        q.x = p.x & 0x1FFFF;
        q.y = p.y;
        pv[pos] = q;
    }
}

// ---------------- degree scan (exclusive, single block) ----------------
__global__ __launch_bounds__(DBIN) void deg_scan_kernel(int* __restrict__ deg) {
    __shared__ int sm[DBIN];
    int t = threadIdx.x;
    int v = deg[t];
    sm[t] = v;
    __syncthreads();
#pragma unroll
    for (int off = 1; off < DBIN; off <<= 1) {
        int u = (t >= off) ? sm[t - off] : 0;
        __syncthreads();
        sm[t] += u;
        __syncthreads();
    }
    deg[t] = sm[t] - v;   // exclusive base
}

// ---------------- degree scatter: rowperm = rows sorted by degree ----------------
__global__ __launch_bounds__(256) void deg_scatter_kernel(const int* __restrict__ row_start,
                                                          int* __restrict__ deg_base,
                                                          int* __restrict__ rowperm, int n) {
    __shared__ int lh[DBIN];
    __shared__ int lbase[DBIN];
    int t = threadIdx.x;
    for (int i = t; i < DBIN; i += 256) lh[i] = 0;
    __syncthreads();
    int r = blockIdx.x * 256 + t;
    int d = 0, lpos = 0;
    bool valid = (r < n);
    if (valid) {
        d = min(row_start[r + 1] - row_start[r], DBIN - 1);
        lpos = atomicAdd(&lh[d], 1);
    }
    __syncthreads();
    for (int i = t; i < DBIN; i += 256) {
        int c = lh[i];
        if (c) lbase[i] = atomicAdd(&deg_base[i], c);
    }
    __syncthreads();
    if (valid) rowperm[lbase[d] + lpos] = r;
}

// ---------------- SPMM (fp8 gather, 8 lanes/row, degree-sorted rows) -> Axm ----------
// 8 lanes per row (uint4 = 16 fp8 per lane), 32 rows per 256-thread block.
__global__ __launch_bounds__(256) void spmm_axm_kernel(const int* __restrict__ row_start,
                                                       const int* __restrict__ rowperm,
                                                       const int2* __restrict__ pv,
                                                       const unsigned char* __restrict__ xf8,
                                                       const unsigned short* __restrict__ xb,
                                                       unsigned short* __restrict__ Axm, int n) {
    int idx = blockIdx.x * 32 + (threadIdx.x >> 3);
    if (idx >= n) return;
    int r = rowperm[idx];
    int l = threadIdx.x & 7;         // lane within row; elems l*16 .. l*16+15
    int s = row_start[r], e = row_start[r + 1];
    float a[16];
#pragma unroll
    for (int q = 0; q < 16; ++q) a[q] = 0.f;
    int j = s;
    for (; j + 1 < e; j += 2) {
        int2 p0 = pv[j], p1 = pv[j + 1];
        uint4 q0 = *reinterpret_cast<const uint4*>(xf8 + (size_t)p0.x * ND + l * 16);
        uint4 q1 = *reinterpret_cast<const uint4*>(xf8 + (size_t)p1.x * ND + l * 16);
        float v0 = __int_as_float(p0.y), v1 = __int_as_float(p1.y);
        f32x2 c;
        c = __builtin_amdgcn_cvt_pk_f32_fp8(q0.x, false); a[0]  += v0 * c.x; a[1]  += v0 * c.y;
        c = __builtin_amdgcn_cvt_pk_f32_fp8(q0.x, true);  a[2]  += v0 * c.x; a[3]  += v0 * c.y;
        c = __builtin_amdgcn_cvt_pk_f32_fp8(q0.y, false); a[4]  += v0 * c.x; a[5]  += v0 * c.y;
        c = __builtin_amdgcn_cvt_pk_f32_fp8(q0.y, true);  a[6]  += v0 * c.x; a[7]  += v0 * c.y;
        c = __builtin_amdgcn_cvt_pk_f32_fp8(q0.z, false); a[8]  += v0 * c.x; a[9]  += v0 * c.y;
        c = __builtin_amdgcn_cvt_pk_f32_fp8(q0.z, true);  a[10] += v0 * c.x; a[11] += v0 * c.y;
        c = __builtin_amdgcn_cvt_pk_f32_fp8(q0.w, false); a[12] += v0 * c.x; a[13] += v0 * c.y;
        c = __builtin_amdgcn_cvt_pk_f32_fp8(q0.w, true);  a[14] += v0 * c.x; a[15] += v0 * c.y;
        c = __builtin_amdgcn_cvt_pk_f32_fp8(q1.x, false); a[0]  += v1 * c.x; a[1]  += v1 * c.y;
        c = __builtin_amdgcn_cvt_pk_f32_fp8(q1.x, true);  a[2]  += v1 * c.x; a[3]  += v1 * c.y;
        c = __builtin_amdgcn_cvt_pk_f32_fp8(q1.y, false); a[4]  += v1 * c.x; a[5]  += v1 * c.y;
        c = __builtin_amdgcn_cvt_pk_f32_fp8(q1.y, true);  a[6]  += v1 * c.x; a[7]  += v1 * c.y;
        c = __builtin_amdgcn_cvt_pk_f32_fp8(q1.z, false); a[8]  += v1 * c.x; a[9]  += v1 * c.y;
        c = __builtin_amdgcn_cvt_pk_f32_fp8(q1.z, true);  a[10] += v1 * c.x; a[11] += v1 * c.y;
        c = __builtin_amdgcn_cvt_pk_f32_fp8(q1.w, false); a[12] += v1 * c.x; a[13] += v1 * c.y;
        c = __builtin_amdgcn_cvt_pk_f32_fp8(q1.w, true);  a[14] += v1 * c.x; a[15] += v1 * c.y;
    }
    if (j < e) {
        int2 p0 = pv[j];
        uint4 q0 = *reinterpret_cast<const uint4*>(xf8 + (size_t)p0.x * ND + l * 16);
        float v0 = __int_as_float(p0.y);
        f32x2 c;
        c = __builtin_amdgcn_cvt_pk_f32_fp8(q0.x, false); a[0]  += v0 * c.x; a[1]  += v0 * c.y;
        c = __builtin_amdgcn_cvt_pk_f32_fp8(q0.x, true);  a[2]  += v0 * c.x; a[3]  += v0 * c.y;
        c = __builtin_amdgcn_cvt_pk_f32_fp8(q0.y, false); a[4]  += v0 * c.x; a[5]  += v0 * c.y;
        c = __builtin_amdgcn_cvt_pk_f32_fp8(q0.y, true);  a[6]  += v0 * c.x; a[7]  += v0 * c.y;
        c = __builtin_amdgcn_cvt_pk_f32_fp8(q0.z, false); a[8]  += v0 * c.x; a[9]  += v0 * c.y;
        c = __builtin_amdgcn_cvt_pk_f32_fp8(q0.z, true);  a[10] += v0 * c.x; a[11] += v0 * c.y;
        c = __builtin_amdgcn_cvt_pk_f32_fp8(q0.w, false); a[12] += v0 * c.x; a[13] += v0 * c.y;
        c = __builtin_amdgcn_cvt_pk_f32_fp8(q0.w, true);  a[14] += v0 * c.x; a[15] += v0 * c.y;
    }
    // own x row (streaming, bf16 precision)
    const unsigned short* xr = xb + (size_t)r * ND + l * 16;
    short8 xv0 = *reinterpret_cast<const short8*>(xr);
    short8 xv1 = *reinterpret_cast<const short8*>(xr + 8);
    short8 pr0, pr1, xm0, xm1;
#pragma unroll
    for (int q = 0; q < 8; ++q) {
        float x0 = bf2f((unsigned short)xv0[q]);
        float x1 = bf2f((unsigned short)xv1[q]);
        pr0[q] = f2bf(x0 + a[q]);
        xm0[q] = f2bf(x0 * a[q]);
        pr1[q] = f2bf(x1 + a[8 + q]);
        xm1[q] = f2bf(x1 * a[8 + q]);
    }
    int sz = r & 7;
    int c0 = 2 * l, c1 = 2 * l + 1;
    unsigned short* rowp = Axm + (size_t)r * 256;
    *reinterpret_cast<short8*>(rowp + ((c0        ^ sz) << 3)) = pr0;
    *reinterpret_cast<short8*>(rowp + ((c1        ^ sz) << 3)) = pr1;
    *reinterpret_cast<short8*>(rowp + (((16 + c0) ^ sz) << 3)) = xm0;
    *reinterpret_cast<short8*>(rowp + (((16 + c1) ^ sz) << 3)) = xm1;
}

// ---------------- prep: Wt2[layer][h][nr][..] pre-swizzled bf16, bsum = bgc+bbi ----------
__global__ void prep_w_kernel(const float* __restrict__ Wgc, const float* __restrict__ bgc,
                              const float* __restrict__ Wbi, const float* __restrict__ bbi,
                              short* __restrict__ Wt2, float* __restrict__ bsum) {
    int z = blockIdx.x;
    int k = blockIdx.y;            // K index within half, 0..127
    int t = threadIdx.x;
    int nn = t & 127;              // N index
    int h  = (t < 128) ? 0 : 1;    // half 0 = Wgc (prop), 1 = Wbi (xm)
    const float* src = h ? (Wbi + ((size_t)z * 128 + k) * 128)
                         : (Wgc + ((size_t)z * 128 + k) * 128);
    float v = src[nn];
    int idx16 = k >> 3, e8 = k & 7;
    size_t addr = ((size_t)(z * 2 + h) * 128 + nn) * 128 + ((idx16 ^ (nn & 7)) << 3) + e8;
    Wt2[addr] = f2bf(v);
    if (k == 0 && t < 128) bsum[z * 128 + t] = bgc[z * 128 + t] + bbi[z * 128 + t];
}

// ---------------- fused layer via MFMA (pure-copy staging) ----------------
__global__ __launch_bounds__(256) void fused_layer_mfma(
        const unsigned short* __restrict__ Axm,   // [(n+pad)][256] pre-swizzled
        const short* __restrict__ Wt2,            // [2][128][128] pre-swizzled (layer base)
        const float* __restrict__ bsum,           // [128]
        float* __restrict__ xout,                 // row stride LDO (fp32 out slice)
        unsigned short* __restrict__ xbout,       // [n][128] bf16 shadow (next x)
        unsigned char* __restrict__ xf8out,       // [n][128] fp8 shadow (next x)
        int n) {
    __shared__ short A_lds[64 * 256];    // 32 KB
    __shared__ short W_lds[128 * 128];   // 32 KB

    const int tid  = threadIdx.x;
    const int row0 = blockIdx.x * 64;
    const int lane = tid & 63;
    const int w    = tid >> 6;
    const int lrow = lane & 15;
    const int kgrp = lane >> 4;

    // ---- async stage: A tile (32KB) + W half 0 (32KB), both LDS-linear copies ----
    {
        const char* gA = (const char*)(Axm + (size_t)row0 * 256) + w * 8192 + lane * 16;
        char*       lA = (char*)A_lds + w * 8192;
        const char* gW = (const char*)Wt2 + w * 8192 + lane * 16;
        char*       lW = (char*)W_lds + w * 8192;
#pragma unroll
        for (int it = 0; it < 8; ++it) {
            gload_lds16(gA + it * 1024, lA + it * 1024);
            gload_lds16(gW + it * 1024, lW + it * 1024);
        }
    }
    asm volatile("s_waitcnt vmcnt(0)" ::: "memory");
    __syncthreads();

    f32x4 acc[8];
#pragma unroll
    for (int nf = 0; nf < 8; ++nf) acc[nf] = (f32x4){0.f, 0.f, 0.f, 0.f};

    const int ar  = w * 16 + lrow;
    const int as_ = ar & 7;

    // ---- half 0 (prop @ Wgc) ----
#pragma unroll
    for (int ksl = 0; ksl < 4; ++ksl) {
        int kkl = ksl * 4 + kgrp;                    // 0..15
        short8 af = *reinterpret_cast<const short8*>(&A_lds[ar * 256 + ((kkl ^ as_) << 3)]);
#pragma unroll
        for (int nf = 0; nf < 8; ++nf) {
            int nr = nf * 16 + lrow;
            short8 bfr = *reinterpret_cast<const short8*>(&W_lds[nr * 128 + ((kkl ^ (nr & 7)) << 3)]);
            acc[nf] = __builtin_amdgcn_mfma_f32_16x16x32_bf16(af, bfr, acc[nf], 0, 0, 0);
        }
    }
    __syncthreads();
    // ---- stage W half 1 ----
    {
        const char* gW = (const char*)Wt2 + 32768 + w * 8192 + lane * 16;
        char*       lW = (char*)W_lds + w * 8192;
#pragma unroll
        for (int it = 0; it < 8; ++it) gload_lds16(gW + it * 1024, lW + it * 1024);
    }
    asm volatile("s_waitcnt vmcnt(0)" ::: "memory");
    __syncthreads();

    // ---- half 1 (xm @ Wbi) ----
#pragma unroll
    for (int ksl = 0; ksl < 4; ++ksl) {
        int kkl = ksl * 4 + kgrp;
        short8 af = *reinterpret_cast<const short8*>(&A_lds[ar * 256 + (((16 + kkl) ^ as_) << 3)]);
#pragma unroll
        for (int nf = 0; nf < 8; ++nf) {
            int nr = nf * 16 + lrow;
            short8 bfr = *reinterpret_cast<const short8*>(&W_lds[nr * 128 + ((kkl ^ (nr & 7)) << 3)]);
            acc[nf] = __builtin_amdgcn_mfma_f32_16x16x32_bf16(af, bfr, acc[nf], 0, 0, 0);
        }
    }

    // ---- epilogue: bias + leaky + row l2-norm; out via nontemporal, bf16 + fp8 shadows ----
    float bsv[8];
#pragma unroll
    for (int nf = 0; nf < 8; ++nf) bsv[nf] = bsum[nf * 16 + lrow];

#pragma unroll
    for (int reg = 0; reg < 4; ++reg) {
        int grow = row0 + w * 16 + kgrp * 4 + reg;
        float v[8];
        float ssq = 0.f;
#pragma unroll
        for (int nf = 0; nf < 8; ++nf) {
            float tv = acc[nf][reg] + bsv[nf];
            tv = tv > 0.f ? tv : ALPHA * tv;
            v[nf] = tv;
            ssq += tv * tv;
        }
        ssq += __shfl_xor(ssq, 1);
        ssq += __shfl_xor(ssq, 2);
        ssq += __shfl_xor(ssq, 4);
        ssq += __shfl_xor(ssq, 8);
        float sc = 1.0f / sqrtf(fmaxf(ssq, L2EPS));
        if (grow < n) {
            float* op = xout + (size_t)grow * LDO;
            unsigned short* bp = xbout + (size_t)grow * ND;
            unsigned char* fp = xf8out + (size_t)grow * ND;
#pragma unroll
            for (int nf = 0; nf < 8; ++nf) {
                float ov = v[nf] * sc;
                __builtin_nontemporal_store(ov, op + nf * 16 + lrow);   // out never re-read
                bp[nf * 16 + lrow] = (unsigned short)f2bf(ov);
                unsigned int u8 = __builtin_amdgcn_cvt_pk_fp8_f32(ov, ov, 0, false);
                fp[nf * 16 + lrow] = (unsigned char)(u8 & 0xff);
            }
        }
    }
}

extern "C" void kernel_launch(void* const* d_in, const int* in_sizes, int n_in,
                              void* d_out, int out_size, void* d_ws, size_t ws_size,
                              hipStream_t stream) {
    const float* emb  = (const float*)d_in[0];
    const int*   erow = (const int*)d_in[1];
    const int*   ecol = (const int*)d_in[2];
    const float* eval = (const float*)d_in[3];
    const float* Wgc  = (const float*)d_in[4];
    const float* bgc  = (const float*)d_in[5];
    const float* Wbi  = (const float*)d_in[6];
    const float* bbi  = (const float*)d_in[7];
    float* out = (float*)d_out;

    const int n        = in_sizes[0] / ND;      // 100000
    const int n_edges  = in_sizes[1];           // 1600000
    const int n_layers = in_sizes[5] / ND;      // 3

    const int nb = (n + RPB - 1) >> 9;          // 196 buckets
    const int ch = (n_edges + NCHUNK - 1) / NCHUNK;
    const int ng = nb * NCHUNK;

    // ---- workspace layout (256B-aligned) ----
    char* ws = (char*)d_ws;
    size_t off = 0;
    auto alloc = [&](size_t bytes) { void* p = ws + off; off = (off + bytes + 255) & ~(size_t)255; return p; };
    unsigned short* xb  = (unsigned short*)alloc((size_t)n * ND * sizeof(short));        // 25.6 MB
    unsigned char*  xf8 = (unsigned char*) alloc((size_t)n * ND);                        // 12.8 MB
    unsigned short* Axm = (unsigned short*)alloc((size_t)(n + 64) * 256 * sizeof(short)); // 51.2 MB (+pad)
    int2*  pv        = (int2*) alloc((size_t)n_edges * sizeof(int2));                    // 12.8 MB
    int2*  tmp       = (int2*) alloc((size_t)n_edges * sizeof(int2));                    // 12.8 MB
    int*   row_start = (int*)  alloc((size_t)(n + 1) * sizeof(int));
    int*   rowperm   = (int*)  alloc((size_t)n * sizeof(int));
    int*   gcnt      = (int*)  alloc((size_t)ng * sizeof(int));
    int*   gscan     = (int*)  alloc((size_t)ng * sizeof(int));
    int*   partials  = (int*)  alloc(512 * sizeof(int));
    int*   deg_hist  = (int*)  alloc(DBIN * sizeof(int));
    short* Wt2       = (short*)alloc((size_t)n_layers * 2 * 128 * 128 * sizeof(short));
    float* bsum      = (float*)alloc((size_t)n_layers * 128 * sizeof(float));
    (void)ws_size;

    // ---- x0 -> out[:, 0:128] + xb + xf8 ----
    {
        int total = n * 32;
        copy_emb_kernel<<<(total + 255) / 256, 256, 0, stream>>>(emb, out, xb,
                                                                 (unsigned int*)xf8, n);
    }

    // ---- weight prep ----
    {
        dim3 g(n_layers, 128);
        prep_w_kernel<<<g, 256, 0, stream>>>(Wgc, bgc, Wbi, bbi, Wt2, bsum);
    }

    // ---- CSR build ----
    hipMemsetAsync(deg_hist, 0, DBIN * sizeof(int), stream);
    bucket_hist_kernel<<<NCHUNK, 256, 0, stream>>>(erow, gcnt, n_edges, nb, ch);
    {
        int nblk = (ng + SCAN_B - 1) / SCAN_B;     // 196
        scanA_kernel<<<nblk, SCAN_B, 0, stream>>>(gcnt, gscan, partials, ng);
        scanB_kernel<<<1, 512, 0, stream>>>(partials, nblk);
    }
    bucket_scatter_kernel<<<NCHUNK, 256, 0, stream>>>(erow, ecol, eval, gscan, partials,
                                                      tmp, n_edges, nb, ch);
    bucket_sort_kernel<<<nb, 256, 0, stream>>>(tmp, gscan, partials, pv, row_start,
                                               deg_hist, n, n_edges, nb);
    deg_scan_kernel<<<1, DBIN, 0, stream>>>(deg_hist);
    deg_scatter_kernel<<<(n + 255) / 256, 256, 0, stream>>>(row_start, deg_hist, rowperm, n);

    // ---- layers ----
    for (int i = 0; i < n_layers; ++i) {
        spmm_axm_kernel<<<(n + 31) / 32, 256, 0, stream>>>(row_start, rowperm, pv, xf8, xb,
                                                           Axm, n);
        fused_layer_mfma<<<(n + 63) / 64, 256, 0, stream>>>(
            Axm, Wt2 + (size_t)i * 2 * 128 * 128, bsum + (size_t)i * 128,
            out + (size_t)(i + 1) * ND, xb, xf8, n);
    }
}

// Round 13
// 317.433 us; speedup vs baseline: 1.8521x; 1.0747x over previous
//
#include <hip/hip_runtime.h>
#include <hip/hip_bf16.h>

#define ND 128
#define LDO 512
#define ALPHA 0.2f
#define L2EPS 1e-12f
#define SCAN_B 256
#define NCHUNK 256     // edge chunks for bucket hist/scatter (== SCAN_B, relied upon!)
#define RPB 512        // rows per bucket (shift 9)

typedef __attribute__((ext_vector_type(8))) short short8;
typedef __attribute__((ext_vector_type(4))) float f32x4;
typedef __attribute__((ext_vector_type(2))) float f32x2;

__device__ __forceinline__ short f2bf(float f) {
    union { float f; unsigned u; } c; c.f = f;
    unsigned u = c.u;
    unsigned r = (u + 0x7fffu + ((u >> 16) & 1u)) >> 16;   // RNE
    return (short)r;
}
__device__ __forceinline__ float bf2f(unsigned short u) {
    union { unsigned u; float f; } c; c.u = ((unsigned)u) << 16;
    return c.f;
}
__device__ __forceinline__ void gload_lds16(const void* g, void* l) {
    __builtin_amdgcn_global_load_lds(
        (const __attribute__((address_space(1))) unsigned int*)g,
        (__attribute__((address_space(3))) unsigned int*)l, 16, 0, 0);
}

// ---------------- copy embeddings into out[:, 0:128], xb (bf16), xf8 (fp8) ----------------
__global__ void copy_emb_kernel(const float* __restrict__ emb, float* __restrict__ out,
                                unsigned short* __restrict__ xb,
                                unsigned int* __restrict__ xf8w, int n) {
    int idx = blockIdx.x * blockDim.x + threadIdx.x;
    int total = n * 32;
    if (idx >= total) return;
    int r = idx >> 5, c4 = idx & 31;
    const float4 v = *reinterpret_cast<const float4*>(emb + (size_t)r * ND + c4 * 4);
    *reinterpret_cast<float4*>(out + (size_t)r * LDO + c4 * 4) = v;
    ushort4 b;
    b.x = (unsigned short)f2bf(v.x); b.y = (unsigned short)f2bf(v.y);
    b.z = (unsigned short)f2bf(v.z); b.w = (unsigned short)f2bf(v.w);
    *reinterpret_cast<ushort4*>(xb + (size_t)r * ND + c4 * 4) = b;
    unsigned int u = __builtin_amdgcn_cvt_pk_fp8_f32(v.x, v.y, 0, false);
    u = __builtin_amdgcn_cvt_pk_fp8_f32(v.z, v.w, u, true);
    xf8w[(size_t)r * 32 + c4] = u;
}

// ---------------- pass A: per-chunk bucket histogram (LDS only) ----------------
__global__ __launch_bounds__(256) void bucket_hist_kernel(const int* __restrict__ erow,
                                                          int* __restrict__ gcnt,
                                                          int n_edges, int nb, int ch) {
    __shared__ int cnt[256];
    int b = blockIdx.x;
    cnt[threadIdx.x] = 0;
    __syncthreads();
    int s = b * ch, e = min(n_edges, s + ch);
    for (int j = s + threadIdx.x; j < e; j += 256) {
        atomicAdd(&cnt[erow[j] >> 9], 1);
    }
    __syncthreads();
    for (int i = threadIdx.x; i < nb; i += 256) gcnt[i * NCHUNK + b] = cnt[i];
}

// ---------------- scanA: per-bucket-block exclusive scan + block sums ----------------
__global__ __launch_bounds__(SCAN_B) void scanA_kernel(const int* __restrict__ in,
                                                       int* __restrict__ outp,
                                                       int* __restrict__ partials, int n) {
    __shared__ int sm[SCAN_B];
    int i = blockIdx.x * SCAN_B + threadIdx.x;
    int v = (i < n) ? in[i] : 0;
    sm[threadIdx.x] = v;
    __syncthreads();
#pragma unroll
    for (int off = 1; off < SCAN_B; off <<= 1) {
        int t = (threadIdx.x >= off) ? sm[threadIdx.x - off] : 0;
        __syncthreads();
        sm[threadIdx.x] += t;
        __syncthreads();
    }
    if (i < n) outp[i] = sm[threadIdx.x] - v;
    if (threadIdx.x == SCAN_B - 1) partials[blockIdx.x] = sm[SCAN_B - 1];
}

// in-LDS exclusive scan of partials[nb] (nb <= 256); result in psc[]
__device__ __forceinline__ void scan_partials(const int* __restrict__ part, int* psc, int nb) {
    int t = threadIdx.x;
    int v = (t < nb) ? part[t] : 0;
    psc[t] = v;
    __syncthreads();
#pragma unroll
    for (int off = 1; off < 256; off <<= 1) {
        int u = (t >= off) ? psc[t - off] : 0;
        __syncthreads();
        psc[t] += u;
        __syncthreads();
    }
    int ex = psc[t] - v;     // exclusive
    __syncthreads();
    psc[t] = ex;
    __syncthreads();
}

// ---------------- pass B: scatter into bucket-grouped tmp ----------------
// base for (bucket i, chunk b) = gscan[i*NCHUNK+b] + psc[i]
__global__ __launch_bounds__(256) void bucket_scatter_kernel(const int* __restrict__ erow,
                                                             const int* __restrict__ ecol,
                                                             const float* __restrict__ eval,
                                                             const int* __restrict__ gscan,
                                                             const int* __restrict__ part,
                                                             int2* __restrict__ tmp,
                                                             int n_edges, int nb, int ch) {
    __shared__ int psc[256];
    __shared__ int cur[256];
    int b = blockIdx.x;
    scan_partials(part, psc, nb);
    for (int i = threadIdx.x; i < nb; i += 256)
        cur[i] = gscan[i * NCHUNK + b] + psc[i];
    __syncthreads();
    int s = b * ch, e = min(n_edges, s + ch);
    for (int j = s + threadIdx.x; j < e; j += 256) {
        int r = erow[j];
        int pos = atomicAdd(&cur[r >> 9], 1);
        int2 p;
        p.x = ecol[j] | ((r & (RPB - 1)) << 17);     // col (17b) | row-low (9b)
        p.y = __float_as_int(eval[j]);
        tmp[pos] = p;
    }
}

// ---------------- pass C: per-bucket counting sort into final CSR pv + row_start ----------
__global__ __launch_bounds__(256) void bucket_sort_kernel(const int2* __restrict__ tmp,
                                                          const int* __restrict__ part,
                                                          int2* __restrict__ pv,
                                                          int* __restrict__ row_start,
                                                          int n, int n_edges, int nb) {
    __shared__ int psc[256];
    __shared__ int hist[RPB];
    __shared__ int cur[RPB];
    __shared__ int sc[256];
    const int t = threadIdx.x;
    const int bkt = blockIdx.x;
    const int r0 = bkt << 9;
    scan_partials(part, psc, nb);
    const int s = psc[bkt];                                   // bucket start (gscan[bkt*NCHUNK]==0)
    const int e = (bkt + 1 < nb) ? psc[bkt + 1] : n_edges;

    for (int i = t; i < RPB; i += 256) hist[i] = 0;
    __syncthreads();
    for (int j = s + t; j < e; j += 256) atomicAdd(&hist[tmp[j].x >> 17], 1);
    __syncthreads();
    int a0 = hist[2 * t], a1 = hist[2 * t + 1];
    sc[t] = a0 + a1;
    __syncthreads();
#pragma unroll
    for (int off = 1; off < 256; off <<= 1) {
        int v = (t >= off) ? sc[t - off] : 0;
        __syncthreads();
        sc[t] += v;
        __syncthreads();
    }
    int base = s + sc[t] - a0 - a1;
    cur[2 * t] = base;
    cur[2 * t + 1] = base + a0;
    __syncthreads();
    int r1 = min(n, r0 + RPB);
    for (int i = t; i < r1 - r0; i += 256) row_start[r0 + i] = cur[i];
    if (t == 0 && r1 == n) row_start[n] = n_edges;
    __syncthreads();
    for (int j = s + t; j < e; j += 256) {
        int2 p = tmp[j];
        int pos = atomicAdd(&cur[p.x >> 17], 1);
        int2 q;
        q.x = p.x & 0x1FFFF;
        q.y = p.y;
        pv[pos] = q;
    }
}

// ---------------- SPMM (fp8 gather, 8 lanes/row) + prop/xm -> pre-swizzled Axm ----------
// 8 lanes per row (uint4 = 16 fp8 per lane), 32 sequential rows per 256-thread block.
__global__ __launch_bounds__(256) void spmm_axm_kernel(const int* __restrict__ row_start,
                                                       const int2* __restrict__ pv,
                                                       const unsigned char* __restrict__ xf8,
                                                       const unsigned short* __restrict__ xb,
                                                       unsigned short* __restrict__ Axm, int n) {
    int r = blockIdx.x * 32 + (threadIdx.x >> 3);
    if (r >= n) return;
    int l = threadIdx.x & 7;         // lane within row; elems l*16 .. l*16+15
    int s = row_start[r], e = row_start[r + 1];
    float a[16];
#pragma unroll
    for (int q = 0; q < 16; ++q) a[q] = 0.f;
    int j = s;
    for (; j + 1 < e; j += 2) {
        int2 p0 = pv[j], p1 = pv[j + 1];
        uint4 q0 = *reinterpret_cast<const uint4*>(xf8 + (size_t)p0.x * ND + l * 16);
        uint4 q1 = *reinterpret_cast<const uint4*>(xf8 + (size_t)p1.x * ND + l * 16);
        float v0 = __int_as_float(p0.y), v1 = __int_as_float(p1.y);
        f32x2 c;
        c = __builtin_amdgcn_cvt_pk_f32_fp8(q0.x, false); a[0]  += v0 * c.x; a[1]  += v0 * c.y;
        c = __builtin_amdgcn_cvt_pk_f32_fp8(q0.x, true);  a[2]  += v0 * c.x; a[3]  += v0 * c.y;
        c = __builtin_amdgcn_cvt_pk_f32_fp8(q0.y, false); a[4]  += v0 * c.x; a[5]  += v0 * c.y;
        c = __builtin_amdgcn_cvt_pk_f32_fp8(q0.y, true);  a[6]  += v0 * c.x; a[7]  += v0 * c.y;
        c = __builtin_amdgcn_cvt_pk_f32_fp8(q0.z, false); a[8]  += v0 * c.x; a[9]  += v0 * c.y;
        c = __builtin_amdgcn_cvt_pk_f32_fp8(q0.z, true);  a[10] += v0 * c.x; a[11] += v0 * c.y;
        c = __builtin_amdgcn_cvt_pk_f32_fp8(q0.w, false); a[12] += v0 * c.x; a[13] += v0 * c.y;
        c = __builtin_amdgcn_cvt_pk_f32_fp8(q0.w, true);  a[14] += v0 * c.x; a[15] += v0 * c.y;
        c = __builtin_amdgcn_cvt_pk_f32_fp8(q1.x, false); a[0]  += v1 * c.x; a[1]  += v1 * c.y;
        c = __builtin_amdgcn_cvt_pk_f32_fp8(q1.x, true);  a[2]  += v1 * c.x; a[3]  += v1 * c.y;
        c = __builtin_amdgcn_cvt_pk_f32_fp8(q1.y, false); a[4]  += v1 * c.x; a[5]  += v1 * c.y;
        c = __builtin_amdgcn_cvt_pk_f32_fp8(q1.y, true);  a[6]  += v1 * c.x; a[7]  += v1 * c.y;
        c = __builtin_amdgcn_cvt_pk_f32_fp8(q1.z, false); a[8]  += v1 * c.x; a[9]  += v1 * c.y;
        c = __builtin_amdgcn_cvt_pk_f32_fp8(q1.z, true);  a[10] += v1 * c.x; a[11] += v1 * c.y;
        c = __builtin_amdgcn_cvt_pk_f32_fp8(q1.w, false); a[12] += v1 * c.x; a[13] += v1 * c.y;
        c = __builtin_amdgcn_cvt_pk_f32_fp8(q1.w, true);  a[14] += v1 * c.x; a[15] += v1 * c.y;
    }
    if (j < e) {
        int2 p0 = pv[j];
        uint4 q0 = *reinterpret_cast<const uint4*>(xf8 + (size_t)p0.x * ND + l * 16);
        float v0 = __int_as_float(p0.y);
        f32x2 c;
        c = __builtin_amdgcn_cvt_pk_f32_fp8(q0.x, false); a[0]  += v0 * c.x; a[1]  += v0 * c.y;
        c = __builtin_amdgcn_cvt_pk_f32_fp8(q0.x, true);  a[2]  += v0 * c.x; a[3]  += v0 * c.y;
        c = __builtin_amdgcn_cvt_pk_f32_fp8(q0.y, false); a[4]  += v0 * c.x; a[5]  += v0 * c.y;
        c = __builtin_amdgcn_cvt_pk_f32_fp8(q0.y, true);  a[6]  += v0 * c.x; a[7]  += v0 * c.y;
        c = __builtin_amdgcn_cvt_pk_f32_fp8(q0.z, false); a[8]  += v0 * c.x; a[9]  += v0 * c.y;
        c = __builtin_amdgcn_cvt_pk_f32_fp8(q0.z, true);  a[10] += v0 * c.x; a[11] += v0 * c.y;
        c = __builtin_amdgcn_cvt_pk_f32_fp8(q0.w, false); a[12] += v0 * c.x; a[13] += v0 * c.y;
        c = __builtin_amdgcn_cvt_pk_f32_fp8(q0.w, true);  a[14] += v0 * c.x; a[15] += v0 * c.y;
    }
    // own x row (streaming, bf16 precision)
    const unsigned short* xr = xb + (size_t)r * ND + l * 16;
    short8 xv0 = *reinterpret_cast<const short8*>(xr);
    short8 xv1 = *reinterpret_cast<const short8*>(xr + 8);
    short8 pr0, pr1, xm0, xm1;
#pragma unroll
    for (int q = 0; q < 8; ++q) {
        float x0 = bf2f((unsigned short)xv0[q]);
        float x1 = bf2f((unsigned short)xv1[q]);
        pr0[q] = f2bf(x0 + a[q]);
        xm0[q] = f2bf(x0 * a[q]);
        pr1[q] = f2bf(x1 + a[8 + q]);
        xm1[q] = f2bf(x1 * a[8 + q]);
    }
    int sz = r & 7;
    int c0 = 2 * l, c1 = 2 * l + 1;
    unsigned short* rowp = Axm + (size_t)r * 256;
    *reinterpret_cast<short8*>(rowp + ((c0        ^ sz) << 3)) = pr0;
    *reinterpret_cast<short8*>(rowp + ((c1        ^ sz) << 3)) = pr1;
    *reinterpret_cast<short8*>(rowp + (((16 + c0) ^ sz) << 3)) = xm0;
    *reinterpret_cast<short8*>(rowp + (((16 + c1) ^ sz) << 3)) = xm1;
}

// ---------------- prep: Wt2[layer][h][nr][..] pre-swizzled bf16, bsum = bgc+bbi ----------
__global__ void prep_w_kernel(const float* __restrict__ Wgc, const float* __restrict__ bgc,
                              const float* __restrict__ Wbi, const float* __restrict__ bbi,
                              short* __restrict__ Wt2, float* __restrict__ bsum) {
    int z = blockIdx.x;
    int k = blockIdx.y;            // K index within half, 0..127
    int t = threadIdx.x;
    int nn = t & 127;              // N index
    int h  = (t < 128) ? 0 : 1;    // half 0 = Wgc (prop), 1 = Wbi (xm)
    const float* src = h ? (Wbi + ((size_t)z * 128 + k) * 128)
                         : (Wgc + ((size_t)z * 128 + k) * 128);
    float v = src[nn];
    int idx16 = k >> 3, e8 = k & 7;
    size_t addr = ((size_t)(z * 2 + h) * 128 + nn) * 128 + ((idx16 ^ (nn & 7)) << 3) + e8;
    Wt2[addr] = f2bf(v);
    if (k == 0 && t < 128) bsum[z * 128 + t] = bgc[z * 128 + t] + bbi[z * 128 + t];
}

// ---------------- fused layer via MFMA (pure-copy staging) ----------------
__global__ __launch_bounds__(256) void fused_layer_mfma(
        const unsigned short* __restrict__ Axm,   // [(n+pad)][256] pre-swizzled
        const short* __restrict__ Wt2,            // [2][128][128] pre-swizzled (layer base)
        const float* __restrict__ bsum,           // [128]
        float* __restrict__ xout,                 // row stride LDO (fp32 out slice)
        unsigned short* __restrict__ xbout,       // [n][128] bf16 shadow (next x)
        unsigned char* __restrict__ xf8out,       // [n][128] fp8 shadow (next x)
        int n) {
    __shared__ short A_lds[64 * 256];    // 32 KB
    __shared__ short W_lds[128 * 128];   // 32 KB

    const int tid  = threadIdx.x;
    const int row0 = blockIdx.x * 64;
    const int lane = tid & 63;
    const int w    = tid >> 6;
    const int lrow = lane & 15;
    const int kgrp = lane >> 4;

    // ---- async stage: A tile (32KB) + W half 0 (32KB), both LDS-linear copies ----
    {
        const char* gA = (const char*)(Axm + (size_t)row0 * 256) + w * 8192 + lane * 16;
        char*       lA = (char*)A_lds + w * 8192;
        const char* gW = (const char*)Wt2 + w * 8192 + lane * 16;
        char*       lW = (char*)W_lds + w * 8192;
#pragma unroll
        for (int it = 0; it < 8; ++it) {
            gload_lds16(gA + it * 1024, lA + it * 1024);
            gload_lds16(gW + it * 1024, lW + it * 1024);
        }
    }
    asm volatile("s_waitcnt vmcnt(0)" ::: "memory");
    __syncthreads();

    f32x4 acc[8];
#pragma unroll
    for (int nf = 0; nf < 8; ++nf) acc[nf] = (f32x4){0.f, 0.f, 0.f, 0.f};

    const int ar  = w * 16 + lrow;
    const int as_ = ar & 7;

    // ---- half 0 (prop @ Wgc) ----
#pragma unroll
    for (int ksl = 0; ksl < 4; ++ksl) {
        int kkl = ksl * 4 + kgrp;                    // 0..15
        short8 af = *reinterpret_cast<const short8*>(&A_lds[ar * 256 + ((kkl ^ as_) << 3)]);
#pragma unroll
        for (int nf = 0; nf < 8; ++nf) {
            int nr = nf * 16 + lrow;
            short8 bfr = *reinterpret_cast<const short8*>(&W_lds[nr * 128 + ((kkl ^ (nr & 7)) << 3)]);
            acc[nf] = __builtin_amdgcn_mfma_f32_16x16x32_bf16(af, bfr, acc[nf], 0, 0, 0);
        }
    }
    __syncthreads();
    // ---- stage W half 1 ----
    {
        const char* gW = (const char*)Wt2 + 32768 + w * 8192 + lane * 16;
        char*       lW = (char*)W_lds + w * 8192;
#pragma unroll
        for (int it = 0; it < 8; ++it) gload_lds16(gW + it * 1024, lW + it * 1024);
    }
    asm volatile("s_waitcnt vmcnt(0)" ::: "memory");
    __syncthreads();

    // ---- half 1 (xm @ Wbi) ----
#pragma unroll
    for (int ksl = 0; ksl < 4; ++ksl) {
        int kkl = ksl * 4 + kgrp;
        short8 af = *reinterpret_cast<const short8*>(&A_lds[ar * 256 + (((16 + kkl) ^ as_) << 3)]);
#pragma unroll
        for (int nf = 0; nf < 8; ++nf) {
            int nr = nf * 16 + lrow;
            short8 bfr = *reinterpret_cast<const short8*>(&W_lds[nr * 128 + ((kkl ^ (nr & 7)) << 3)]);
            acc[nf] = __builtin_amdgcn_mfma_f32_16x16x32_bf16(af, bfr, acc[nf], 0, 0, 0);
        }
    }

    // ---- epilogue: bias + leaky + row l2-norm; out via nontemporal, bf16 + fp8 shadows ----
    float bsv[8];
#pragma unroll
    for (int nf = 0; nf < 8; ++nf) bsv[nf] = bsum[nf * 16 + lrow];

#pragma unroll
    for (int reg = 0; reg < 4; ++reg) {
        int grow = row0 + w * 16 + kgrp * 4 + reg;
        float v[8];
        float ssq = 0.f;
#pragma unroll
        for (int nf = 0; nf < 8; ++nf) {
            float tv = acc[nf][reg] + bsv[nf];
            tv = tv > 0.f ? tv : ALPHA * tv;
            v[nf] = tv;
            ssq += tv * tv;
        }
        ssq += __shfl_xor(ssq, 1);
        ssq += __shfl_xor(ssq, 2);
        ssq += __shfl_xor(ssq, 4);
        ssq += __shfl_xor(ssq, 8);
        float sc = 1.0f / sqrtf(fmaxf(ssq, L2EPS));
        if (grow < n) {
            float* op = xout + (size_t)grow * LDO;
            unsigned short* bp = xbout + (size_t)grow * ND;
            unsigned char* fp = xf8out + (size_t)grow * ND;
#pragma unroll
            for (int nf = 0; nf < 8; ++nf) {
                float ov = v[nf] * sc;
                __builtin_nontemporal_store(ov, op + nf * 16 + lrow);   // out never re-read
                bp[nf * 16 + lrow] = (unsigned short)f2bf(ov);
                unsigned int u8 = __builtin_amdgcn_cvt_pk_fp8_f32(ov, ov, 0, false);
                fp[nf * 16 + lrow] = (unsigned char)(u8 & 0xff);
            }
        }
    }
}

extern "C" void kernel_launch(void* const* d_in, const int* in_sizes, int n_in,
                              void* d_out, int out_size, void* d_ws, size_t ws_size,
                              hipStream_t stream) {
    const float* emb  = (const float*)d_in[0];
    const int*   erow = (const int*)d_in[1];
    const int*   ecol = (const int*)d_in[2];
    const float* eval = (const float*)d_in[3];
    const float* Wgc  = (const float*)d_in[4];
    const float* bgc  = (const float*)d_in[5];
    const float* Wbi  = (const float*)d_in[6];
    const float* bbi  = (const float*)d_in[7];
    float* out = (float*)d_out;

    const int n        = in_sizes[0] / ND;      // 100000
    const int n_edges  = in_sizes[1];           // 1600000
    const int n_layers = in_sizes[5] / ND;      // 3

    const int nb = (n + RPB - 1) >> 9;          // 196 buckets
    const int ch = (n_edges + NCHUNK - 1) / NCHUNK;
    const int ng = nb * NCHUNK;

    // ---- workspace layout (256B-aligned) ----
    char* ws = (char*)d_ws;
    size_t off = 0;
    auto alloc = [&](size_t bytes) { void* p = ws + off; off = (off + bytes + 255) & ~(size_t)255; return p; };
    unsigned short* xb  = (unsigned short*)alloc((size_t)n * ND * sizeof(short));        // 25.6 MB
    unsigned char*  xf8 = (unsigned char*) alloc((size_t)n * ND);                        // 12.8 MB
    unsigned short* Axm = (unsigned short*)alloc((size_t)(n + 64) * 256 * sizeof(short)); // 51.2 MB (+pad)
    int2*  pv        = (int2*) alloc((size_t)n_edges * sizeof(int2));                    // 12.8 MB
    int2*  tmp       = (int2*) alloc((size_t)n_edges * sizeof(int2));                    // 12.8 MB
    int*   row_start = (int*)  alloc((size_t)(n + 1) * sizeof(int));
    int*   gcnt      = (int*)  alloc((size_t)ng * sizeof(int));
    int*   gscan     = (int*)  alloc((size_t)ng * sizeof(int));
    int*   partials  = (int*)  alloc(512 * sizeof(int));
    short* Wt2       = (short*)alloc((size_t)n_layers * 2 * 128 * 128 * sizeof(short));
    float* bsum      = (float*)alloc((size_t)n_layers * 128 * sizeof(float));
    (void)ws_size;

    // ---- x0 -> out[:, 0:128] + xb + xf8 ----
    {
        int total = n * 32;
        copy_emb_kernel<<<(total + 255) / 256, 256, 0, stream>>>(emb, out, xb,
                                                                 (unsigned int*)xf8, n);
    }

    // ---- weight prep ----
    {
        dim3 g(n_layers, 128);
        prep_w_kernel<<<g, 256, 0, stream>>>(Wgc, bgc, Wbi, bbi, Wt2, bsum);
    }

    // ---- CSR build (hist -> scanA -> scatter -> sort; partials scanned in-kernel) ----
    bucket_hist_kernel<<<NCHUNK, 256, 0, stream>>>(erow, gcnt, n_edges, nb, ch);
    {
        int nblk = (ng + SCAN_B - 1) / SCAN_B;     // 196
        scanA_kernel<<<nblk, SCAN_B, 0, stream>>>(gcnt, gscan, partials, ng);
    }
    bucket_scatter_kernel<<<NCHUNK, 256, 0, stream>>>(erow, ecol, eval, gscan, partials,
                                                      tmp, n_edges, nb, ch);
    bucket_sort_kernel<<<nb, 256, 0, stream>>>(tmp, partials, pv, row_start,
                                               n, n_edges, nb);

    // ---- layers ----
    for (int i = 0; i < n_layers; ++i) {
        spmm_axm_kernel<<<(n + 31) / 32, 256, 0, stream>>>(row_start, pv, xf8, xb, Axm, n);
        fused_layer_mfma<<<(n + 63) / 64, 256, 0, stream>>>(
            Axm, Wt2 + (size_t)i * 2 * 128 * 128, bsum + (size_t)i * 128,
            out + (size_t)(i + 1) * ND, xb, xf8, n);
    }
}

// Round 17
// 301.062 us; speedup vs baseline: 1.9529x; 1.0544x over previous
//
#include <hip/hip_runtime.h>
#include <hip/hip_bf16.h>

#define ND 128
#define LDO 512
#define ALPHA 0.2f
#define L2EPS 1e-12f
#define SCAN_B 256
#define NCHUNK 256     // edge chunks for bucket hist/scatter (== SCAN_B, relied upon!)
#define RPB 512        // rows per bucket (shift 9)

typedef __attribute__((ext_vector_type(8))) short short8;
typedef __attribute__((ext_vector_type(4))) float f32x4;
typedef __attribute__((ext_vector_type(2))) float f32x2;

__device__ __forceinline__ short f2bf(float f) {
    union { float f; unsigned u; } c; c.f = f;
    unsigned u = c.u;
    unsigned r = (u + 0x7fffu + ((u >> 16) & 1u)) >> 16;   // RNE
    return (short)r;
}
__device__ __forceinline__ float bf2f(unsigned short u) {
    union { unsigned u; float f; } c; c.u = ((unsigned)u) << 16;
    return c.f;
}
__device__ __forceinline__ void gload_lds16(const void* g, void* l) {
    __builtin_amdgcn_global_load_lds(
        (const __attribute__((address_space(1))) unsigned int*)g,
        (__attribute__((address_space(3))) unsigned int*)l, 16, 0, 0);
}

// ---------------- prologue: bucket_hist (blocks 0..NCHUNK) + prep_w + copy_emb ----------
__global__ __launch_bounds__(256) void prologue_kernel(
        const float* __restrict__ emb, float* __restrict__ out,
        unsigned short* __restrict__ xb, unsigned int* __restrict__ xf8w,
        const int* __restrict__ erow, int* __restrict__ gcnt,
        const float* __restrict__ Wgc, const float* __restrict__ bgc,
        const float* __restrict__ Wbi, const float* __restrict__ bbi,
        short* __restrict__ Wt2, float* __restrict__ bsum,
        int n, int n_edges, int nb, int ch, int n_prep) {
    __shared__ int cnt[256];
    const int b = blockIdx.x;
    const int t = threadIdx.x;
    if (b < NCHUNK) {
        // ---- bucket histogram ----
        cnt[t] = 0;
        __syncthreads();
        int s = b * ch, e = min(n_edges, s + ch);
        for (int j = s + t; j < e; j += 256) atomicAdd(&cnt[erow[j] >> 9], 1);
        __syncthreads();
        for (int i = t; i < nb; i += 256) gcnt[i * NCHUNK + b] = cnt[i];
    } else if (b < NCHUNK + n_prep) {
        // ---- weight prep: zb = layer*128 + k ----
        int zb = b - NCHUNK;
        int z = zb >> 7, k = zb & 127;
        int nn = t & 127;
        int h  = (t < 128) ? 0 : 1;
        const float* src = h ? (Wbi + ((size_t)z * 128 + k) * 128)
                             : (Wgc + ((size_t)z * 128 + k) * 128);
        float v = src[nn];
        int idx16 = k >> 3, e8 = k & 7;
        size_t addr = ((size_t)(z * 2 + h) * 128 + nn) * 128 + ((idx16 ^ (nn & 7)) << 3) + e8;
        Wt2[addr] = f2bf(v);
        if (k == 0 && t < 128) bsum[z * 128 + t] = bgc[z * 128 + t] + bbi[z * 128 + t];
    } else {
        // ---- copy emb -> out[:,0:128] (NT) + xb + xf8 ----
        int idx = (b - NCHUNK - n_prep) * 256 + t;
        int total = n * 32;
        if (idx >= total) return;
        int r = idx >> 5, c4 = idx & 31;
        const float* ep = emb + (size_t)r * ND + c4 * 4;
        float4 v;
        v.x = __builtin_nontemporal_load(ep + 0);
        v.y = __builtin_nontemporal_load(ep + 1);
        v.z = __builtin_nontemporal_load(ep + 2);
        v.w = __builtin_nontemporal_load(ep + 3);
        float* op = out + (size_t)r * LDO + c4 * 4;
        __builtin_nontemporal_store(v.x, op + 0);
        __builtin_nontemporal_store(v.y, op + 1);
        __builtin_nontemporal_store(v.z, op + 2);
        __builtin_nontemporal_store(v.w, op + 3);
        ushort4 bb;
        bb.x = (unsigned short)f2bf(v.x); bb.y = (unsigned short)f2bf(v.y);
        bb.z = (unsigned short)f2bf(v.z); bb.w = (unsigned short)f2bf(v.w);
        *reinterpret_cast<ushort4*>(xb + (size_t)r * ND + c4 * 4) = bb;
        unsigned int u = __builtin_amdgcn_cvt_pk_fp8_f32(v.x, v.y, 0, false);
        u = __builtin_amdgcn_cvt_pk_fp8_f32(v.z, v.w, u, true);
        xf8w[(size_t)r * 32 + c4] = u;
    }
}

// ---------------- scanA: per-bucket-block exclusive scan + block sums ----------------
__global__ __launch_bounds__(SCAN_B) void scanA_kernel(const int* __restrict__ in,
                                                       int* __restrict__ outp,
                                                       int* __restrict__ partials, int n) {
    __shared__ int sm[SCAN_B];
    int i = blockIdx.x * SCAN_B + threadIdx.x;
    int v = (i < n) ? in[i] : 0;
    sm[threadIdx.x] = v;
    __syncthreads();
#pragma unroll
    for (int off = 1; off < SCAN_B; off <<= 1) {
        int t = (threadIdx.x >= off) ? sm[threadIdx.x - off] : 0;
        __syncthreads();
        sm[threadIdx.x] += t;
        __syncthreads();
    }
    if (i < n) outp[i] = sm[threadIdx.x] - v;
    if (threadIdx.x == SCAN_B - 1) partials[blockIdx.x] = sm[SCAN_B - 1];
}

// in-LDS exclusive scan of partials[nb] (nb <= 256); result in psc[]
__device__ __forceinline__ void scan_partials(const int* __restrict__ part, int* psc, int nb) {
    int t = threadIdx.x;
    int v = (t < nb) ? part[t] : 0;
    psc[t] = v;
    __syncthreads();
#pragma unroll
    for (int off = 1; off < 256; off <<= 1) {
        int u = (t >= off) ? psc[t - off] : 0;
        __syncthreads();
        psc[t] += u;
        __syncthreads();
    }
    int ex = psc[t] - v;     // exclusive
    __syncthreads();
    psc[t] = ex;
    __syncthreads();
}

// ---------------- pass B: scatter into bucket-grouped tmp ----------------
__global__ __launch_bounds__(256) void bucket_scatter_kernel(const int* __restrict__ erow,
                                                             const int* __restrict__ ecol,
                                                             const float* __restrict__ eval,
                                                             const int* __restrict__ gscan,
                                                             const int* __restrict__ part,
                                                             int2* __restrict__ tmp,
                                                             int n_edges, int nb, int ch) {
    __shared__ int psc[256];
    __shared__ int cur[256];
    int b = blockIdx.x;
    scan_partials(part, psc, nb);
    for (int i = threadIdx.x; i < nb; i += 256)
        cur[i] = gscan[i * NCHUNK + b] + psc[i];
    __syncthreads();
    int s = b * ch, e = min(n_edges, s + ch);
    for (int j = s + threadIdx.x; j < e; j += 256) {
        int r = erow[j];
        int pos = atomicAdd(&cur[r >> 9], 1);
        int2 p;
        p.x = ecol[j] | ((r & (RPB - 1)) << 17);     // col (17b) | row-low (9b)
        p.y = __float_as_int(eval[j]);
        tmp[pos] = p;
    }
}

// ---------------- pass C: per-bucket counting sort into final CSR pv + row_start ----------
__global__ __launch_bounds__(256) void bucket_sort_kernel(const int2* __restrict__ tmp,
                                                          const int* __restrict__ part,
                                                          int2* __restrict__ pv,
                                                          int* __restrict__ row_start,
                                                          int n, int n_edges, int nb) {
    __shared__ int psc[256];
    __shared__ int hist[RPB];
    __shared__ int cur[RPB];
    __shared__ int sc[256];
    const int t = threadIdx.x;
    const int bkt = blockIdx.x;
    const int r0 = bkt << 9;
    scan_partials(part, psc, nb);
    const int s = psc[bkt];
    const int e = (bkt + 1 < nb) ? psc[bkt + 1] : n_edges;

    for (int i = t; i < RPB; i += 256) hist[i] = 0;
    __syncthreads();
    for (int j = s + t; j < e; j += 256) atomicAdd(&hist[tmp[j].x >> 17], 1);
    __syncthreads();
    int a0 = hist[2 * t], a1 = hist[2 * t + 1];
    sc[t] = a0 + a1;
    __syncthreads();
#pragma unroll
    for (int off = 1; off < 256; off <<= 1) {
        int v = (t >= off) ? sc[t - off] : 0;
        __syncthreads();
        sc[t] += v;
        __syncthreads();
    }
    int base = s + sc[t] - a0 - a1;
    cur[2 * t] = base;
    cur[2 * t + 1] = base + a0;
    __syncthreads();
    int r1 = min(n, r0 + RPB);
    for (int i = t; i < r1 - r0; i += 256) row_start[r0 + i] = cur[i];
    if (t == 0 && r1 == n) row_start[n] = n_edges;
    __syncthreads();
    for (int j = s + t; j < e; j += 256) {
        int2 p = tmp[j];
        int pos = atomicAdd(&cur[p.x >> 17], 1);
        int2 q;
        q.x = p.x & 0x1FFFF;
        q.y = p.y;
        pv[pos] = q;
    }
}

// ---------------- SPMM (fp8 gather, 8 lanes/row) + prop/xm -> pre-swizzled Axm ----------
__global__ __launch_bounds__(256) void spmm_axm_kernel(const int* __restrict__ row_start,
                                                       const int2* __restrict__ pv,
                                                       const unsigned char* __restrict__ xf8,
                                                       const unsigned short* __restrict__ xb,
                                                       unsigned short* __restrict__ Axm, int n) {
    int r = blockIdx.x * 32 + (threadIdx.x >> 3);
    if (r >= n) return;
    int l = threadIdx.x & 7;         // lane within row; elems l*16 .. l*16+15
    int s = row_start[r], e = row_start[r + 1];
    float a[16];
#pragma unroll
    for (int q = 0; q < 16; ++q) a[q] = 0.f;
    int j = s;
    for (; j + 1 < e; j += 2) {
        int2 p0 = pv[j], p1 = pv[j + 1];
        uint4 q0 = *reinterpret_cast<const uint4*>(xf8 + (size_t)p0.x * ND + l * 16);
        uint4 q1 = *reinterpret_cast<const uint4*>(xf8 + (size_t)p1.x * ND + l * 16);
        float v0 = __int_as_float(p0.y), v1 = __int_as_float(p1.y);
        f32x2 c;
        c = __builtin_amdgcn_cvt_pk_f32_fp8(q0.x, false); a[0]  += v0 * c.x; a[1]  += v0 * c.y;
        c = __builtin_amdgcn_cvt_pk_f32_fp8(q0.x, true);  a[2]  += v0 * c.x; a[3]  += v0 * c.y;
        c = __builtin_amdgcn_cvt_pk_f32_fp8(q0.y, false); a[4]  += v0 * c.x; a[5]  += v0 * c.y;
        c = __builtin_amdgcn_cvt_pk_f32_fp8(q0.y, true);  a[6]  += v0 * c.x; a[7]  += v0 * c.y;
        c = __builtin_amdgcn_cvt_pk_f32_fp8(q0.z, false); a[8]  += v0 * c.x; a[9]  += v0 * c.y;
        c = __builtin_amdgcn_cvt_pk_f32_fp8(q0.z, true);  a[10] += v0 * c.x; a[11] += v0 * c.y;
        c = __builtin_amdgcn_cvt_pk_f32_fp8(q0.w, false); a[12] += v0 * c.x; a[13] += v0 * c.y;
        c = __builtin_amdgcn_cvt_pk_f32_fp8(q0.w, true);  a[14] += v0 * c.x; a[15] += v0 * c.y;
        c = __builtin_amdgcn_cvt_pk_f32_fp8(q1.x, false); a[0]  += v1 * c.x; a[1]  += v1 * c.y;
        c = __builtin_amdgcn_cvt_pk_f32_fp8(q1.x, true);  a[2]  += v1 * c.x; a[3]  += v1 * c.y;
        c = __builtin_amdgcn_cvt_pk_f32_fp8(q1.y, false); a[4]  += v1 * c.x; a[5]  += v1 * c.y;
        c = __builtin_amdgcn_cvt_pk_f32_fp8(q1.y, true);  a[6]  += v1 * c.x; a[7]  += v1 * c.y;
        c = __builtin_amdgcn_cvt_pk_f32_fp8(q1.z, false); a[8]  += v1 * c.x; a[9]  += v1 * c.y;
        c = __builtin_amdgcn_cvt_pk_f32_fp8(q1.z, true);  a[10] += v1 * c.x; a[11] += v1 * c.y;
        c = __builtin_amdgcn_cvt_pk_f32_fp8(q1.w, false); a[12] += v1 * c.x; a[13] += v1 * c.y;
        c = __builtin_amdgcn_cvt_pk_f32_fp8(q1.w, true);  a[14] += v1 * c.x; a[15] += v1 * c.y;
    }
    if (j < e) {
        int2 p0 = pv[j];
        uint4 q0 = *reinterpret_cast<const uint4*>(xf8 + (size_t)p0.x * ND + l * 16);
        float v0 = __int_as_float(p0.y);
        f32x2 c;
        c = __builtin_amdgcn_cvt_pk_f32_fp8(q0.x, false); a[0]  += v0 * c.x; a[1]  += v0 * c.y;
        c = __builtin_amdgcn_cvt_pk_f32_fp8(q0.x, true);  a[2]  += v0 * c.x; a[3]  += v0 * c.y;
        c = __builtin_amdgcn_cvt_pk_f32_fp8(q0.y, false); a[4]  += v0 * c.x; a[5]  += v0 * c.y;
        c = __builtin_amdgcn_cvt_pk_f32_fp8(q0.y, true);  a[6]  += v0 * c.x; a[7]  += v0 * c.y;
        c = __builtin_amdgcn_cvt_pk_f32_fp8(q0.z, false); a[8]  += v0 * c.x; a[9]  += v0 * c.y;
        c = __builtin_amdgcn_cvt_pk_f32_fp8(q0.z, true);  a[10] += v0 * c.x; a[11] += v0 * c.y;
        c = __builtin_amdgcn_cvt_pk_f32_fp8(q0.w, false); a[12] += v0 * c.x; a[13] += v0 * c.y;
        c = __builtin_amdgcn_cvt_pk_f32_fp8(q0.w, true);  a[14] += v0 * c.x; a[15] += v0 * c.y;
    }
    // own x row (streaming, bf16 precision)
    const unsigned short* xr = xb + (size_t)r * ND + l * 16;
    short8 xv0 = *reinterpret_cast<const short8*>(xr);
    short8 xv1 = *reinterpret_cast<const short8*>(xr + 8);
    short8 pr0, pr1, xm0, xm1;
#pragma unroll
    for (int q = 0; q < 8; ++q) {
        float x0 = bf2f((unsigned short)xv0[q]);
        float x1 = bf2f((unsigned short)xv1[q]);
        pr0[q] = f2bf(x0 + a[q]);
        xm0[q] = f2bf(x0 * a[q]);
        pr1[q] = f2bf(x1 + a[8 + q]);
        xm1[q] = f2bf(x1 * a[8 + q]);
    }
    int sz = r & 7;
    int c0 = 2 * l, c1 = 2 * l + 1;
    unsigned short* rowp = Axm + (size_t)r * 256;
    *reinterpret_cast<short8*>(rowp + ((c0        ^ sz) << 3)) = pr0;
    *reinterpret_cast<short8*>(rowp + ((c1        ^ sz) << 3)) = pr1;
    *reinterpret_cast<short8*>(rowp + (((16 + c0) ^ sz) << 3)) = xm0;
    *reinterpret_cast<short8*>(rowp + (((16 + c1) ^ sz) << 3)) = xm1;
}

// ---------------- fused layer via MFMA (pure-copy staging; W1 via reg prefetch) ----------
__global__ __launch_bounds__(256) void fused_layer_mfma(
        const unsigned short* __restrict__ Axm,   // [(n+pad)][256] pre-swizzled
        const short* __restrict__ Wt2,            // [2][128][128] pre-swizzled (layer base)
        const float* __restrict__ bsum,           // [128]
        float* __restrict__ xout,                 // row stride LDO (fp32 out slice)
        unsigned short* __restrict__ xbout,       // [n][128] bf16 shadow (next x)
        unsigned char* __restrict__ xf8out,       // [n][128] fp8 shadow (next x)
        int n) {
    __shared__ short A_lds[64 * 256];    // 32 KB
    __shared__ short W_lds[128 * 128];   // 32 KB

    const int tid  = threadIdx.x;
    const int row0 = blockIdx.x * 64;
    const int lane = tid & 63;
    const int w    = tid >> 6;
    const int lrow = lane & 15;
    const int kgrp = lane >> 4;

    // ---- async stage: A tile (32KB) + W half 0 (32KB), both LDS-linear copies ----
    {
        const char* gA = (const char*)(Axm + (size_t)row0 * 256) + w * 8192 + lane * 16;
        char*       lA = (char*)A_lds + w * 8192;
        const char* gW = (const char*)Wt2 + w * 8192 + lane * 16;
        char*       lW = (char*)W_lds + w * 8192;
#pragma unroll
        for (int it = 0; it < 8; ++it) {
            gload_lds16(gA + it * 1024, lA + it * 1024);
            gload_lds16(gW + it * 1024, lW + it * 1024);
        }
    }
    asm volatile("s_waitcnt vmcnt(0)" ::: "memory");
    __syncthreads();

    // ---- issue W half-1 into registers: latency hides under half-0 MFMA (T14) ----
    short8 w1r[8];
    {
        const char* gW1 = (const char*)Wt2 + 32768 + w * 8192 + lane * 16;
#pragma unroll
        for (int it = 0; it < 8; ++it)
            w1r[it] = *reinterpret_cast<const short8*>(gW1 + it * 1024);
    }

    f32x4 acc[8];
#pragma unroll
    for (int nf = 0; nf < 8; ++nf) acc[nf] = (f32x4){0.f, 0.f, 0.f, 0.f};

    const int ar  = w * 16 + lrow;
    const int as_ = ar & 7;

    // ---- half 0 (prop @ Wgc) ----
#pragma unroll
    for (int ksl = 0; ksl < 4; ++ksl) {
        int kkl = ksl * 4 + kgrp;                    // 0..15
        short8 af = *reinterpret_cast<const short8*>(&A_lds[ar * 256 + ((kkl ^ as_) << 3)]);
#pragma unroll
        for (int nf = 0; nf < 8; ++nf) {
            int nr = nf * 16 + lrow;
            short8 bfr = *reinterpret_cast<const short8*>(&W_lds[nr * 128 + ((kkl ^ (nr & 7)) << 3)]);
            acc[nf] = __builtin_amdgcn_mfma_f32_16x16x32_bf16(af, bfr, acc[nf], 0, 0, 0);
        }
    }
    __syncthreads();                               // half-0 W reads complete
    // ---- write W half 1 from registers (per-lane address: base + lane*16!) ----
    {
        char* lW = (char*)W_lds + w * 8192 + lane * 16;
#pragma unroll
        for (int it = 0; it < 8; ++it)
            *reinterpret_cast<short8*>(lW + it * 1024) = w1r[it];
    }
    __syncthreads();

    // ---- half 1 (xm @ Wbi) ----
#pragma unroll
    for (int ksl = 0; ksl < 4; ++ksl) {
        int kkl = ksl * 4 + kgrp;
        short8 af = *reinterpret_cast<const short8*>(&A_lds[ar * 256 + (((16 + kkl) ^ as_) << 3)]);
#pragma unroll
        for (int nf = 0; nf < 8; ++nf) {
            int nr = nf * 16 + lrow;
            short8 bfr = *reinterpret_cast<const short8*>(&W_lds[nr * 128 + ((kkl ^ (nr & 7)) << 3)]);
            acc[nf] = __builtin_amdgcn_mfma_f32_16x16x32_bf16(af, bfr, acc[nf], 0, 0, 0);
        }
    }

    // ---- epilogue: bias + leaky + row l2-norm; out via nontemporal, bf16 + fp8 shadows ----
    float bsv[8];
#pragma unroll
    for (int nf = 0; nf < 8; ++nf) bsv[nf] = bsum[nf * 16 + lrow];

#pragma unroll
    for (int reg = 0; reg < 4; ++reg) {
        int grow = row0 + w * 16 + kgrp * 4 + reg;
        float v[8];
        float ssq = 0.f;
#pragma unroll
        for (int nf = 0; nf < 8; ++nf) {
            float tv = acc[nf][reg] + bsv[nf];
            tv = tv > 0.f ? tv : ALPHA * tv;
            v[nf] = tv;
            ssq += tv * tv;
        }
        ssq += __shfl_xor(ssq, 1);
        ssq += __shfl_xor(ssq, 2);
        ssq += __shfl_xor(ssq, 4);
        ssq += __shfl_xor(ssq, 8);
        float sc = 1.0f / sqrtf(fmaxf(ssq, L2EPS));
        if (grow < n) {
            float* op = xout + (size_t)grow * LDO;
            unsigned short* bp = xbout + (size_t)grow * ND;
            unsigned char* fp = xf8out + (size_t)grow * ND;
#pragma unroll
            for (int nf = 0; nf < 8; ++nf) {
                float ov = v[nf] * sc;
                __builtin_nontemporal_store(ov, op + nf * 16 + lrow);   // out never re-read
                bp[nf * 16 + lrow] = (unsigned short)f2bf(ov);
                unsigned int u8 = __builtin_amdgcn_cvt_pk_fp8_f32(ov, ov, 0, false);
                fp[nf * 16 + lrow] = (unsigned char)(u8 & 0xff);
            }
        }
    }
}

extern "C" void kernel_launch(void* const* d_in, const int* in_sizes, int n_in,
                              void* d_out, int out_size, void* d_ws, size_t ws_size,
                              hipStream_t stream) {
    const float* emb  = (const float*)d_in[0];
    const int*   erow = (const int*)d_in[1];
    const int*   ecol = (const int*)d_in[2];
    const float* eval = (const float*)d_in[3];
    const float* Wgc  = (const float*)d_in[4];
    const float* bgc  = (const float*)d_in[5];
    const float* Wbi  = (const float*)d_in[6];
    const float* bbi  = (const float*)d_in[7];
    float* out = (float*)d_out;

    const int n        = in_sizes[0] / ND;      // 100000
    const int n_edges  = in_sizes[1];           // 1600000
    const int n_layers = in_sizes[5] / ND;      // 3

    const int nb = (n + RPB - 1) >> 9;          // 196 buckets
    const int ch = (n_edges + NCHUNK - 1) / NCHUNK;
    const int ng = nb * NCHUNK;

    // ---- workspace layout (256B-aligned) ----
    char* ws = (char*)d_ws;
    size_t off = 0;
    auto alloc = [&](size_t bytes) { void* p = ws + off; off = (off + bytes + 255) & ~(size_t)255; return p; };
    unsigned short* xb  = (unsigned short*)alloc((size_t)n * ND * sizeof(short));        // 25.6 MB
    unsigned char*  xf8 = (unsigned char*) alloc((size_t)n * ND);                        // 12.8 MB
    unsigned short* Axm = (unsigned short*)alloc((size_t)(n + 64) * 256 * sizeof(short)); // 51.2 MB (+pad)
    int2*  pv        = (int2*) alloc((size_t)n_edges * sizeof(int2));                    // 12.8 MB
    int2*  tmp       = (int2*) alloc((size_t)n_edges * sizeof(int2));                    // 12.8 MB
    int*   row_start = (int*)  alloc((size_t)(n + 1) * sizeof(int));
    int*   gcnt      = (int*)  alloc((size_t)ng * sizeof(int));
    int*   gscan     = (int*)  alloc((size_t)ng * sizeof(int));
    int*   partials  = (int*)  alloc(512 * sizeof(int));
    short* Wt2       = (short*)alloc((size_t)n_layers * 2 * 128 * 128 * sizeof(short));
    float* bsum      = (float*)alloc((size_t)n_layers * 128 * sizeof(float));
    (void)ws_size;

    // ---- prologue: hist + weight prep + emb copy, one kernel ----
    {
        int n_prep = n_layers * 128;                      // 384
        int n_copy = (n * 32 + 255) / 256;                // 12500
        int grid = NCHUNK + n_prep + n_copy;
        prologue_kernel<<<grid, 256, 0, stream>>>(emb, out, xb, (unsigned int*)xf8,
                                                  erow, gcnt, Wgc, bgc, Wbi, bbi,
                                                  Wt2, bsum, n, n_edges, nb, ch, n_prep);
    }

    // ---- CSR build ----
    {
        int nblk = (ng + SCAN_B - 1) / SCAN_B;     // 196
        scanA_kernel<<<nblk, SCAN_B, 0, stream>>>(gcnt, gscan, partials, ng);
    }
    bucket_scatter_kernel<<<NCHUNK, 256, 0, stream>>>(erow, ecol, eval, gscan, partials,
                                                      tmp, n_edges, nb, ch);
    bucket_sort_kernel<<<nb, 256, 0, stream>>>(tmp, partials, pv, row_start,
                                               n, n_edges, nb);

    // ---- layers ----
    for (int i = 0; i < n_layers; ++i) {
        spmm_axm_kernel<<<(n + 31) / 32, 256, 0, stream>>>(row_start, pv, xf8, xb, Axm, n);
        fused_layer_mfma<<<(n + 63) / 64, 256, 0, stream>>>(
            Axm, Wt2 + (size_t)i * 2 * 128 * 128, bsum + (size_t)i * 128,
            out + (size_t)(i + 1) * ND, xb, xf8, n);
    }
}